// Round 7
// baseline (875.369 us; speedup 1.0000x reference)
//
#include <hip/hip_runtime.h>

// 2-layer GCN. Aggregation = bucket-LDS scatter over pre-binned edge pairs.
// Pipeline: detect -> binA (bin edges by dst>>8 into gstage) -> cntB (degree)
//   -> gemm1 (g1b = bf16((x@W1)*dinv)) -> scat1 (h1b = bf16(dinv*(agg+self)+b1))
//   -> gemm2 (g2b = bf16((h1@W2)*dinv)) -> scat2 (out = dinv*(agg+self)+b2)

#define NPB 256     // nodes per bucket (dst >> 8)
#define BCAP 4096   // max edges per bucket (mean ~3070, sd ~55)
#define TILE_E 2048 // edges per binning block
#define BIN_T 512   // threads in binning/scatter kernels

__device__ __forceinline__ float bf2f(unsigned short u) {
    unsigned int v = ((unsigned int)u) << 16;
    return __builtin_bit_cast(float, v);
}
__device__ __forceinline__ unsigned short f2bf(float f) {
    unsigned int u = __builtin_bit_cast(unsigned int, f);
    u += 0x7FFFu + ((u >> 16) & 1u);  // round-to-nearest-even
    return (unsigned short)(u >> 16);
}

__device__ __forceinline__ int edge_val(const void* ei, int is64, long long idx) {
    if (is64) return (int)((const long long*)ei)[idx];
    return ((const int*)ei)[idx];
}

// int64 vs int32 edge buffer detect; also zero bucket_wp[512].
__global__ void k_detect(const unsigned int* __restrict__ w, int nelems, int* flag,
                         int* __restrict__ bucket_wp) {
    __shared__ unsigned int red[BIN_T];
    bucket_wp[threadIdx.x] = 0;
    unsigned int acc = 0;
    int limit = nelems < 16384 ? nelems : 16384;
    for (int i = 1 + 2 * (int)threadIdx.x; i < limit; i += 2 * BIN_T) acc |= w[i];
    red[threadIdx.x] = acc;
    __syncthreads();
    for (int s = BIN_T / 2; s > 0; s >>= 1) {
        if ((int)threadIdx.x < s) red[threadIdx.x] |= red[threadIdx.x + s];
        __syncthreads();
    }
    if (threadIdx.x == 0) *flag = (red[0] == 0u) ? 1 : 0;
}

// Pass A: bin edges by bucket = dst>>8 into gstage (bucket-major, BCAP stride).
// Packed: src (bits 0..19) | (dst&255)<<20. LDS-staged for chunked writes.
__launch_bounds__(BIN_T)
__global__ void k_binA(const void* __restrict__ ei, const int* __restrict__ flag, int E,
                       int nb, unsigned int* __restrict__ gstage, int* __restrict__ bucket_wp) {
    __shared__ int lcnt[BIN_T];
    __shared__ int lboff[BIN_T];
    __shared__ int lrank[BIN_T];
    __shared__ int gbase[BIN_T];
    __shared__ int sh[BIN_T];
    __shared__ unsigned int spair[TILE_E];
    __shared__ unsigned short sbuck[TILE_E];
    int is64 = *flag;
    int t = threadIdx.x;
    int base_e = blockIdx.x * TILE_E;
    int ne = E - base_e;
    if (ne > TILE_E) ne = TILE_E;

    lcnt[t] = 0;
    lrank[t] = 0;
    __syncthreads();

    int myb[4];
    unsigned int mypair[4];
#pragma unroll
    for (int k = 0; k < 4; ++k) {
        int idx = t + k * BIN_T;
        myb[k] = -1;
        if (idx < ne) {
            long long e = base_e + idx;
            int s = edge_val(ei, is64, e);
            int d = edge_val(ei, is64, (long long)E + e);
            int b = d >> 8;
            myb[k] = b;
            mypair[k] = (unsigned int)s | ((unsigned int)(d & (NPB - 1)) << 20);
            atomicAdd(&lcnt[b], 1);
        }
    }
    __syncthreads();

    int v0 = lcnt[t];
    sh[t] = v0;
    __syncthreads();
    for (int st = 1; st < BIN_T; st <<= 1) {
        int u = (t >= st) ? sh[t - st] : 0;
        __syncthreads();
        sh[t] += u;
        __syncthreads();
    }
    lboff[t] = sh[t] - v0;
    if (t < nb && v0 > 0) gbase[t] = atomicAdd(&bucket_wp[t], v0);
    __syncthreads();

#pragma unroll
    for (int k = 0; k < 4; ++k) {
        int b = myb[k];
        if (b >= 0) {
            int r = atomicAdd(&lrank[b], 1);
            int slot = lboff[b] + r;
            spair[slot] = mypair[k];
            sbuck[slot] = (unsigned short)b;
        }
    }
    __syncthreads();

    for (int j = t; j < ne; j += BIN_T) {
        int b = sbuck[j];
        int pos = gbase[b] + (j - lboff[b]);
        if (pos < BCAP) gstage[(size_t)b * BCAP + pos] = spair[j];
    }
}

// Per-bucket degree histogram -> cnt.
__global__ void k_cntB(const unsigned int* __restrict__ gstage,
                       const int* __restrict__ bucket_wp, int* __restrict__ cnt, int n_nodes) {
    __shared__ int hist[NPB];
    int b = blockIdx.x, t = threadIdx.x;
    hist[t] = 0;
    __syncthreads();
    int cb = bucket_wp[b];
    if (cb > BCAP) cb = BCAP;
    const unsigned int* gp = gstage + (size_t)b * BCAP;
    for (int j = t; j < cb; j += NPB) atomicAdd(&hist[(gp[j] >> 20) & (NPB - 1)], 1);
    __syncthreads();
    int node = b * NPB + t;
    if (node < n_nodes) cnt[node] = hist[t];
}

// g1b[n] = bf16((x[n]@W1)*dinv[n]); dinv from cnt+1. 16 nodes/block.
__launch_bounds__(256)
__global__ void k_gemm1(const float* __restrict__ x, const float* __restrict__ W1,
                        const int* __restrict__ cnt, float* __restrict__ dinv,
                        unsigned short* __restrict__ g1b, int n_nodes) {
    __shared__ float Ws[64][64];
    __shared__ float Xs[16][64];
    int t = threadIdx.x;
    for (int i = t; i < 1024; i += 256) ((float4*)Ws)[i] = ((const float4*)W1)[i];
    int node0 = blockIdx.x * 16;
    {
        int nl = t >> 4, c = t & 15;
        int node = node0 + nl;
        float4 v = make_float4(0.f, 0.f, 0.f, 0.f);
        if (node < n_nodes) v = ((const float4*)(x + (size_t)node * 64))[c];
        ((float4*)Xs[nl])[c] = v;
    }
    __syncthreads();
    int f = t & 63;
#pragma unroll
    for (int it = 0; it < 4; ++it) {
        int nl = (t >> 6) + 4 * it;
        int node = node0 + nl;
        if (node >= n_nodes) continue;
        float acc = 0.f;
#pragma unroll
        for (int k = 0; k < 64; ++k) acc += Xs[nl][k] * Ws[k][f];
        float di = rsqrtf((float)(cnt[node] + 1));
        g1b[(size_t)node * 64 + f] = f2bf(acc * di);
        if (f == 0) dinv[node] = di;
    }
}

// Layer-1 aggregation: one block per bucket, agg[256][64] fp32 in LDS (64 KB).
// Lane layout: q = lane>>4 (edge slot), fl = lane&15 (4 feats). 4 gathers in flight.
__launch_bounds__(BIN_T)
__global__ void k_scat1(const unsigned int* __restrict__ gstage,
                        const int* __restrict__ bucket_wp,
                        const unsigned short* __restrict__ g1b, const float* __restrict__ dinv,
                        const float* __restrict__ b1, unsigned short* __restrict__ h1b,
                        int n_nodes) {
    __shared__ float agg[NPB][64];  // exactly 65536 B
    int b = blockIdx.x, t = threadIdx.x;
    for (int i = t; i < NPB * 16; i += BIN_T) ((float4*)agg)[i] = make_float4(0.f, 0.f, 0.f, 0.f);
    __syncthreads();
    int cb = bucket_wp[b];
    if (cb > BCAP) cb = BCAP;
    const unsigned int* gp = gstage + (size_t)b * BCAP;
    int wid = t >> 6, lane = t & 63;
    int q = lane >> 4, fl = lane & 15;
    for (int start = wid * 64; start < cb; start += BIN_T) {
        int rem = cb - start;
        if (rem > 64) rem = 64;
        unsigned int p = (lane < rem) ? gp[start + lane] : 0u;
        for (int g = 0; g < rem; g += 16) {
            int e0 = g + q, e1 = g + 4 + q, e2 = g + 8 + q, e3 = g + 12 + q;
            unsigned int p0 = (unsigned int)__shfl((int)p, e0);
            unsigned int p1 = (unsigned int)__shfl((int)p, e1);
            unsigned int p2 = (unsigned int)__shfl((int)p, e2);
            unsigned int p3 = (unsigned int)__shfl((int)p, e3);
            ushort4 u0 = ((const ushort4*)(g1b + (size_t)(p0 & 0xFFFFFu) * 64))[fl];
            ushort4 u1 = ((const ushort4*)(g1b + (size_t)(p1 & 0xFFFFFu) * 64))[fl];
            ushort4 u2 = ((const ushort4*)(g1b + (size_t)(p2 & 0xFFFFFu) * 64))[fl];
            ushort4 u3 = ((const ushort4*)(g1b + (size_t)(p3 & 0xFFFFFu) * 64))[fl];
            if (e0 < rem) {
                float* ap = &agg[(p0 >> 20) & (NPB - 1)][fl * 4];
                atomicAdd(ap + 0, bf2f(u0.x)); atomicAdd(ap + 1, bf2f(u0.y));
                atomicAdd(ap + 2, bf2f(u0.z)); atomicAdd(ap + 3, bf2f(u0.w));
            }
            if (e1 < rem) {
                float* ap = &agg[(p1 >> 20) & (NPB - 1)][fl * 4];
                atomicAdd(ap + 0, bf2f(u1.x)); atomicAdd(ap + 1, bf2f(u1.y));
                atomicAdd(ap + 2, bf2f(u1.z)); atomicAdd(ap + 3, bf2f(u1.w));
            }
            if (e2 < rem) {
                float* ap = &agg[(p2 >> 20) & (NPB - 1)][fl * 4];
                atomicAdd(ap + 0, bf2f(u2.x)); atomicAdd(ap + 1, bf2f(u2.y));
                atomicAdd(ap + 2, bf2f(u2.z)); atomicAdd(ap + 3, bf2f(u2.w));
            }
            if (e3 < rem) {
                float* ap = &agg[(p3 >> 20) & (NPB - 1)][fl * 4];
                atomicAdd(ap + 0, bf2f(u3.x)); atomicAdd(ap + 1, bf2f(u3.y));
                atomicAdd(ap + 2, bf2f(u3.z)); atomicAdd(ap + 3, bf2f(u3.w));
            }
        }
    }
    __syncthreads();
    // epilogue: h1b[node] = bf16(dinv*(agg + g1b[node]) + b1), float4 chunks
    for (int idx = t; idx < NPB * 16; idx += BIN_T) {
        int nl = idx >> 4, c = idx & 15;
        int node = b * NPB + nl;
        if (node >= n_nodes) break;
        float di = dinv[node];
        ushort4 srow = ((const ushort4*)(g1b + (size_t)node * 64))[c];
        float* ap = &agg[nl][c * 4];
        ushort4 o;
        o.x = f2bf(di * (ap[0] + bf2f(srow.x)) + b1[c * 4 + 0]);
        o.y = f2bf(di * (ap[1] + bf2f(srow.y)) + b1[c * 4 + 1]);
        o.z = f2bf(di * (ap[2] + bf2f(srow.z)) + b1[c * 4 + 2]);
        o.w = f2bf(di * (ap[3] + bf2f(srow.w)) + b1[c * 4 + 3]);
        ((ushort4*)(h1b + (size_t)node * 64))[c] = o;
    }
}

// g2b[n] = bf16((h1[n]@W2)*dinv[n]). 16 nodes/block, bf16 in/out.
__launch_bounds__(256)
__global__ void k_gemm2(const unsigned short* __restrict__ h1b, const float* __restrict__ dinv,
                        const float* __restrict__ W2, unsigned short* __restrict__ g2b,
                        int n_nodes) {
    __shared__ float Ws[64][32];
    __shared__ float Hs[16][64];
    int t = threadIdx.x;
    for (int i = t; i < 64 * 32; i += 256) Ws[i >> 5][i & 31] = W2[i];
    int node0 = blockIdx.x * 16;
    {
        int nl = t >> 4, c = t & 15;
        int node = node0 + nl;
        ushort4 u = make_ushort4(0, 0, 0, 0);
        if (node < n_nodes) u = ((const ushort4*)(h1b + (size_t)node * 64))[c];
        Hs[nl][c * 4 + 0] = bf2f(u.x);
        Hs[nl][c * 4 + 1] = bf2f(u.y);
        Hs[nl][c * 4 + 2] = bf2f(u.z);
        Hs[nl][c * 4 + 3] = bf2f(u.w);
    }
    __syncthreads();
#pragma unroll
    for (int it = 0; it < 2; ++it) {
        int o = it * 256 + t;
        int nl = o >> 5, f = o & 31;
        int node = node0 + nl;
        if (node >= n_nodes) continue;
        float acc = 0.f;
#pragma unroll
        for (int k = 0; k < 64; ++k) acc += Hs[nl][k] * Ws[k][f];
        g2b[(size_t)node * 32 + f] = f2bf(acc * dinv[node]);
    }
}

// Layer-2 aggregation: agg[256][32] fp32 (32 KB). q = lane>>3 (8 slots), fl = lane&7.
__launch_bounds__(BIN_T)
__global__ void k_scat2(const unsigned int* __restrict__ gstage,
                        const int* __restrict__ bucket_wp,
                        const unsigned short* __restrict__ g2b, const float* __restrict__ dinv,
                        const float* __restrict__ b2, float* __restrict__ out, int n_nodes) {
    __shared__ float agg[NPB][32];  // 32768 B
    int b = blockIdx.x, t = threadIdx.x;
    for (int i = t; i < NPB * 8; i += BIN_T) ((float4*)agg)[i] = make_float4(0.f, 0.f, 0.f, 0.f);
    __syncthreads();
    int cb = bucket_wp[b];
    if (cb > BCAP) cb = BCAP;
    const unsigned int* gp = gstage + (size_t)b * BCAP;
    int wid = t >> 6, lane = t & 63;
    int q = lane >> 3, fl = lane & 7;
    for (int start = wid * 64; start < cb; start += BIN_T) {
        int rem = cb - start;
        if (rem > 64) rem = 64;
        unsigned int p = (lane < rem) ? gp[start + lane] : 0u;
        for (int g = 0; g < rem; g += 32) {
            int e0 = g + q, e1 = g + 8 + q, e2 = g + 16 + q, e3 = g + 24 + q;
            unsigned int p0 = (unsigned int)__shfl((int)p, e0);
            unsigned int p1 = (unsigned int)__shfl((int)p, e1);
            unsigned int p2 = (unsigned int)__shfl((int)p, e2);
            unsigned int p3 = (unsigned int)__shfl((int)p, e3);
            ushort4 u0 = ((const ushort4*)(g2b + (size_t)(p0 & 0xFFFFFu) * 32))[fl];
            ushort4 u1 = ((const ushort4*)(g2b + (size_t)(p1 & 0xFFFFFu) * 32))[fl];
            ushort4 u2 = ((const ushort4*)(g2b + (size_t)(p2 & 0xFFFFFu) * 32))[fl];
            ushort4 u3 = ((const ushort4*)(g2b + (size_t)(p3 & 0xFFFFFu) * 32))[fl];
            if (e0 < rem) {
                float* ap = &agg[(p0 >> 20) & (NPB - 1)][fl * 4];
                atomicAdd(ap + 0, bf2f(u0.x)); atomicAdd(ap + 1, bf2f(u0.y));
                atomicAdd(ap + 2, bf2f(u0.z)); atomicAdd(ap + 3, bf2f(u0.w));
            }
            if (e1 < rem) {
                float* ap = &agg[(p1 >> 20) & (NPB - 1)][fl * 4];
                atomicAdd(ap + 0, bf2f(u1.x)); atomicAdd(ap + 1, bf2f(u1.y));
                atomicAdd(ap + 2, bf2f(u1.z)); atomicAdd(ap + 3, bf2f(u1.w));
            }
            if (e2 < rem) {
                float* ap = &agg[(p2 >> 20) & (NPB - 1)][fl * 4];
                atomicAdd(ap + 0, bf2f(u2.x)); atomicAdd(ap + 1, bf2f(u2.y));
                atomicAdd(ap + 2, bf2f(u2.z)); atomicAdd(ap + 3, bf2f(u2.w));
            }
            if (e3 < rem) {
                float* ap = &agg[(p3 >> 20) & (NPB - 1)][fl * 4];
                atomicAdd(ap + 0, bf2f(u3.x)); atomicAdd(ap + 1, bf2f(u3.y));
                atomicAdd(ap + 2, bf2f(u3.z)); atomicAdd(ap + 3, bf2f(u3.w));
            }
        }
    }
    __syncthreads();
    // epilogue: out[node] = dinv*(agg + g2b[node]) + b2, float4 chunks
    for (int idx = t; idx < NPB * 8; idx += BIN_T) {
        int nl = idx >> 3, c = idx & 7;
        int node = b * NPB + nl;
        if (node >= n_nodes) break;
        float di = dinv[node];
        ushort4 srow = ((const ushort4*)(g2b + (size_t)node * 32))[c];
        float* ap = &agg[nl][c * 4];
        float4 o;
        o.x = di * (ap[0] + bf2f(srow.x)) + b2[c * 4 + 0];
        o.y = di * (ap[1] + bf2f(srow.y)) + b2[c * 4 + 1];
        o.z = di * (ap[2] + bf2f(srow.z)) + b2[c * 4 + 2];
        o.w = di * (ap[3] + bf2f(srow.w)) + b2[c * 4 + 3];
        ((float4*)(out + (size_t)node * 32))[c] = o;
    }
}

extern "C" void kernel_launch(void* const* d_in, const int* in_sizes, int n_in,
                              void* d_out, int out_size, void* d_ws, size_t ws_size,
                              hipStream_t stream) {
    const float* x  = (const float*)d_in[0];
    const void*  ei = d_in[1];
    const float* W1 = (const float*)d_in[2];
    const float* b1 = (const float*)d_in[3];
    const float* W2 = (const float*)d_in[4];
    const float* b2 = (const float*)d_in[5];
    float* out = (float*)d_out;

    const int n_nodes = in_sizes[0] / 64;
    const int E = in_sizes[1] / 2;
    const int nb = (n_nodes + NPB - 1) / NPB;  // 391 for 100k (<= BIN_T)

    char* p = (char*)d_ws;
    auto carve = [&](size_t bytes) {
        char* r = p;
        p += (bytes + 255) / 256 * 256;
        return r;
    };
    int* flag      = (int*)carve(sizeof(int));
    int* bucket_wp = (int*)carve(BIN_T * sizeof(int));
    int* cnt       = (int*)carve((size_t)n_nodes * sizeof(int));
    float* dinv    = (float*)carve((size_t)n_nodes * sizeof(float));
    unsigned int* gstage = (unsigned int*)carve((size_t)nb * BCAP * sizeof(unsigned int));
    unsigned short* g1b  = (unsigned short*)carve((size_t)n_nodes * 64 * sizeof(unsigned short));
    unsigned short* h1b  = (unsigned short*)carve((size_t)n_nodes * 64 * sizeof(unsigned short));
    unsigned short* g2b  = (unsigned short*)carve((size_t)n_nodes * 32 * sizeof(unsigned short));

    k_detect<<<1, BIN_T, 0, stream>>>((const unsigned int*)ei, in_sizes[1], flag, bucket_wp);
    k_binA<<<(E + TILE_E - 1) / TILE_E, BIN_T, 0, stream>>>(ei, flag, E, nb, gstage, bucket_wp);
    k_cntB<<<nb, NPB, 0, stream>>>(gstage, bucket_wp, cnt, n_nodes);
    k_gemm1<<<(n_nodes + 15) / 16, 256, 0, stream>>>(x, W1, cnt, dinv, g1b, n_nodes);
    k_scat1<<<nb, BIN_T, 0, stream>>>(gstage, bucket_wp, g1b, dinv, b1, h1b, n_nodes);
    k_gemm2<<<(n_nodes + 15) / 16, 256, 0, stream>>>(h1b, dinv, W2, g2b, n_nodes);
    k_scat2<<<nb, BIN_T, 0, stream>>>(gstage, bucket_wp, g2b, dinv, b2, out, n_nodes);
}

// Round 8
// 175.056 us; speedup vs baseline: 5.0005x; 5.0005x over previous
//
#include <hip/hip_runtime.h>

// 2-layer GCN, pull aggregation over ELL (padded, W=20) adjacency.
// detect -> binA (bucket by dst>>9) -> ellB (ELL + overflow list + degree)
//  -> gemm1 (g1b = bf16((x@W1)*dinv), zero-row at index n)
//  -> ell1 (h1f fp32 = sum of 20 gathered rows + self; branchless, 20 loads in flight)
//  -> oflow1 (fp32 atomics for deg>20 leftovers)
//  -> gemm2 (reads h1f, applies di*raw+b1 on the fly, writes g2b bf16)
//  -> ell2 (out fp32 = raw layer-2 sum) -> oflow2 -> final (out = di*out + b2)

#define TPB 256
#define NPB 512     // nodes per bucket (dst >> 9)
#define BCAP 8192   // max edges per bucket (mean ~6122)
#define TILE_E 2048 // edges per binning block
#define W_ELL 20    // ELL width (Poisson(12): ~2% rows overflow)

__device__ __forceinline__ float bf2f(unsigned short u) {
    unsigned int v = ((unsigned int)u) << 16;
    return __builtin_bit_cast(float, v);
}
__device__ __forceinline__ unsigned short f2bf(float f) {
    unsigned int u = __builtin_bit_cast(unsigned int, f);
    u += 0x7FFFu + ((u >> 16) & 1u);  // RNE
    return (unsigned short)(u >> 16);
}
__device__ __forceinline__ int edge_val(const void* ei, int is64, long long idx) {
    if (is64) return (int)((const long long*)ei)[idx];
    return ((const int*)ei)[idx];
}

// detect int64 vs int32; zero bucket_wp + ovf_cnt + the two zero-rows.
__global__ void k_detect(const unsigned int* __restrict__ w, int nelems, int* flag,
                         int* __restrict__ bucket_wp, int* __restrict__ ovf_cnt,
                         unsigned short* __restrict__ g1b, unsigned short* __restrict__ g2b,
                         int n_nodes) {
    __shared__ unsigned int red[TPB];
    int t = threadIdx.x;
    bucket_wp[t] = 0;
    if (t == 0) *ovf_cnt = 0;
    if (t < 64) g1b[(size_t)n_nodes * 64 + t] = 0;
    if (t < 32) g2b[(size_t)n_nodes * 32 + t] = 0;
    unsigned int acc = 0;
    int limit = nelems < 16384 ? nelems : 16384;
    for (int i = 1 + 2 * t; i < limit; i += 2 * TPB) acc |= w[i];
    red[t] = acc;
    __syncthreads();
    for (int s = TPB / 2; s > 0; s >>= 1) {
        if (t < s) red[t] |= red[t + s];
        __syncthreads();
    }
    if (t == 0) *flag = (red[0] == 0u) ? 1 : 0;
}

// Pass A: bin edges by bucket = dst>>9 into gstage (bucket-major, BCAP stride).
// Packed: src (bits 0..19) | (dst&511) << 20. LDS-staged chunked writes.
__launch_bounds__(TPB)
__global__ void k_binA(const void* __restrict__ ei, const int* __restrict__ flag, int E,
                       int nb, unsigned int* __restrict__ gstage, int* __restrict__ bucket_wp) {
    __shared__ int lcnt[256];
    __shared__ int lboff[256];
    __shared__ int lrank[256];
    __shared__ int gbase[256];
    __shared__ int sh[256];
    __shared__ unsigned int spair[TILE_E];
    __shared__ unsigned char sbuck[TILE_E];
    int is64 = *flag;
    int t = threadIdx.x;
    int base_e = blockIdx.x * TILE_E;
    int ne = E - base_e;
    if (ne > TILE_E) ne = TILE_E;

    lcnt[t] = 0;
    lrank[t] = 0;
    __syncthreads();

    int myb[8];
    unsigned int mypair[8];
#pragma unroll
    for (int k = 0; k < 8; ++k) {
        int idx = t + k * TPB;
        myb[k] = -1;
        if (idx < ne) {
            long long e = base_e + idx;
            int s = edge_val(ei, is64, e);
            int d = edge_val(ei, is64, (long long)E + e);
            int b = d >> 9;
            myb[k] = b;
            mypair[k] = (unsigned int)s | ((unsigned int)(d & (NPB - 1)) << 20);
            atomicAdd(&lcnt[b], 1);
        }
    }
    __syncthreads();

    int v0 = lcnt[t];
    sh[t] = v0;
    __syncthreads();
    for (int st = 1; st < TPB; st <<= 1) {
        int u = (t >= st) ? sh[t - st] : 0;
        __syncthreads();
        sh[t] += u;
        __syncthreads();
    }
    lboff[t] = sh[t] - v0;
    if (t < nb && v0 > 0) gbase[t] = atomicAdd(&bucket_wp[t], v0);
    __syncthreads();

#pragma unroll
    for (int k = 0; k < 8; ++k) {
        int b = myb[k];
        if (b >= 0) {
            int r = atomicAdd(&lrank[b], 1);
            int slot = lboff[b] + r;
            spair[slot] = mypair[k];
            sbuck[slot] = (unsigned char)b;
        }
    }
    __syncthreads();

    for (int j = t; j < ne; j += TPB) {
        int b = sbuck[j];
        int pos = gbase[b] + (j - lboff[b]);
        if (pos < BCAP) gstage[(size_t)b * BCAP + pos] = spair[j];
    }
}

// Per bucket: build ELL slab (512 nodes x 20) in LDS, overflow to global list.
__launch_bounds__(512)
__global__ void k_ellB(const unsigned int* __restrict__ gstage, const int* __restrict__ bucket_wp,
                       int* __restrict__ ell, int* __restrict__ cnt, int* __restrict__ ovf,
                       int* __restrict__ ovf_cnt, int n_nodes) {
    __shared__ int lrank[NPB];
    __shared__ int slab[NPB * W_ELL];  // 40 KB
    int b = blockIdx.x, t = threadIdx.x;
    int zr = n_nodes;
    lrank[t] = 0;
    for (int j = t; j < NPB * W_ELL; j += 512) slab[j] = zr;
    __syncthreads();
    int cb = bucket_wp[b];
    if (cb > BCAP) cb = BCAP;
    const unsigned int* gp = gstage + (size_t)b * BCAP;
    for (int j = t; j < cb; j += 512) {
        unsigned int w = gp[j];
        int dl = (int)(w >> 20);
        int src = (int)(w & 0xFFFFFu);
        int r = atomicAdd(&lrank[dl], 1);
        if (r < W_ELL) {
            slab[dl * W_ELL + r] = src;
        } else {
            int o = atomicAdd(ovf_cnt, 1);
            ovf[2 * o] = src;
            ovf[2 * o + 1] = b * NPB + dl;
        }
    }
    __syncthreads();
    int node = b * NPB + t;
    if (node < n_nodes) cnt[node] = lrank[t];
    for (int j = t; j < NPB * W_ELL; j += 512) ell[(size_t)b * (NPB * W_ELL) + j] = slab[j];
}

// g1b[n] = bf16((x[n]@W1)*dinv[n]); dinv from cnt+1. 16 nodes/block.
__launch_bounds__(TPB)
__global__ void k_gemm1(const float* __restrict__ x, const float* __restrict__ W1,
                        const int* __restrict__ cnt, float* __restrict__ dinv,
                        unsigned short* __restrict__ g1b, int n_nodes) {
    __shared__ float Ws[64][64];
    __shared__ float Xs[16][64];
    int t = threadIdx.x;
    for (int i = t; i < 1024; i += TPB) ((float4*)Ws)[i] = ((const float4*)W1)[i];
    int node0 = blockIdx.x * 16;
    {
        int nl = t >> 4, c = t & 15;
        int node = node0 + nl;
        float4 v = make_float4(0.f, 0.f, 0.f, 0.f);
        if (node < n_nodes) v = ((const float4*)(x + (size_t)node * 64))[c];
        ((float4*)Xs[nl])[c] = v;
    }
    __syncthreads();
    int f = t & 63;
#pragma unroll
    for (int it = 0; it < 4; ++it) {
        int nl = (t >> 6) + 4 * it;
        int node = node0 + nl;
        if (node >= n_nodes) continue;
        float acc = 0.f;
#pragma unroll
        for (int k = 0; k < 64; ++k) acc += Xs[nl][k] * Ws[k][f];
        float di = rsqrtf((float)(cnt[node] + 1));
        g1b[(size_t)node * 64 + f] = f2bf(acc * di);
        if (f == 0) dinv[node] = di;
    }
}

#define GATH64(S)                                                              \
    {                                                                          \
        ushort4 u = ((const ushort4*)(g1b + (size_t)(S) * 64))[fl];            \
        a0 += bf2f(u.x); a1 += bf2f(u.y); a2 += bf2f(u.z); a3 += bf2f(u.w);    \
    }

// Layer-1 ELL pull: 16-lane group per node, 20 branchless gathers in flight.
// h1f[node] = fp32 raw sum (neighbors + self), pre-scale.
__launch_bounds__(TPB)
__global__ void k_ell1(const int* __restrict__ ell, const unsigned short* __restrict__ g1b,
                       float* __restrict__ h1f, int n_nodes) {
    int t = threadIdx.x;
    int lane = t & 63;
    int g = lane >> 4, fl = lane & 15;
    int node = blockIdx.x * 16 + (t >> 6) * 4 + g;
    if (node >= n_nodes) return;
    const int4* ep = (const int4*)(ell + (size_t)node * W_ELL);
    int4 i0 = ep[0], i1 = ep[1], i2 = ep[2], i3 = ep[3], i4 = ep[4];
    ushort4 su = ((const ushort4*)(g1b + (size_t)node * 64))[fl];
    float a0 = bf2f(su.x), a1 = bf2f(su.y), a2 = bf2f(su.z), a3 = bf2f(su.w);
    GATH64(i0.x) GATH64(i0.y) GATH64(i0.z) GATH64(i0.w)
    GATH64(i1.x) GATH64(i1.y) GATH64(i1.z) GATH64(i1.w)
    GATH64(i2.x) GATH64(i2.y) GATH64(i2.z) GATH64(i2.w)
    GATH64(i3.x) GATH64(i3.y) GATH64(i3.z) GATH64(i3.w)
    GATH64(i4.x) GATH64(i4.y) GATH64(i4.z) GATH64(i4.w)
    float4 o = make_float4(a0, a1, a2, a3);
    ((float4*)(h1f + (size_t)node * 64))[fl] = o;
}

// Overflow cleanup layer 1: fp32 atomics into h1f.
__global__ void k_oflow1(const int* __restrict__ ovf, const int* __restrict__ ovf_cnt,
                         const unsigned short* __restrict__ g1b, float* __restrict__ h1f) {
    int n = *ovf_cnt;
    int total = n * 16;
    for (int i = blockIdx.x * blockDim.x + threadIdx.x; i < total;
         i += gridDim.x * blockDim.x) {
        int e = i >> 4, fl = i & 15;
        int src = ovf[2 * e], dst = ovf[2 * e + 1];
        ushort4 u = ((const ushort4*)(g1b + (size_t)src * 64))[fl];
        float* hp = h1f + (size_t)dst * 64 + fl * 4;
        atomicAdd(hp + 0, bf2f(u.x));
        atomicAdd(hp + 1, bf2f(u.y));
        atomicAdd(hp + 2, bf2f(u.z));
        atomicAdd(hp + 3, bf2f(u.w));
    }
}

// g2b[n] = bf16(((di*h1f[n] + b1) @ W2) * di). 16 nodes/block.
__launch_bounds__(TPB)
__global__ void k_gemm2(const float* __restrict__ h1f, const float* __restrict__ dinv,
                        const float* __restrict__ b1, const float* __restrict__ W2,
                        unsigned short* __restrict__ g2b, int n_nodes) {
    __shared__ float Ws[64][32];
    __shared__ float Hs[16][64];
    int t = threadIdx.x;
    for (int i = t; i < 64 * 32; i += TPB) Ws[i >> 5][i & 31] = W2[i];
    int node0 = blockIdx.x * 16;
    {
        int nl = t >> 4, c = t & 15;
        int node = node0 + nl;
        float4 v = make_float4(0.f, 0.f, 0.f, 0.f);
        float di = 0.f;
        if (node < n_nodes) {
            v = ((const float4*)(h1f + (size_t)node * 64))[c];
            di = dinv[node];
        }
        Hs[nl][c * 4 + 0] = di * v.x + b1[c * 4 + 0];
        Hs[nl][c * 4 + 1] = di * v.y + b1[c * 4 + 1];
        Hs[nl][c * 4 + 2] = di * v.z + b1[c * 4 + 2];
        Hs[nl][c * 4 + 3] = di * v.w + b1[c * 4 + 3];
    }
    __syncthreads();
#pragma unroll
    for (int it = 0; it < 2; ++it) {
        int o = it * TPB + t;
        int nl = o >> 5, f = o & 31;
        int node = node0 + nl;
        if (node >= n_nodes) continue;
        float acc = 0.f;
#pragma unroll
        for (int k = 0; k < 64; ++k) acc += Hs[nl][k] * Ws[k][f];
        g2b[(size_t)node * 32 + f] = f2bf(acc * dinv[node]);
    }
}

#define GATH32(S)                                                              \
    {                                                                          \
        ushort4 u = ((const ushort4*)(g2b + (size_t)(S) * 32))[fl];            \
        a0 += bf2f(u.x); a1 += bf2f(u.y); a2 += bf2f(u.z); a3 += bf2f(u.w);    \
    }

// Layer-2 ELL pull: 8-lane group per node. out = raw fp32 sum (pre-scale).
__launch_bounds__(TPB)
__global__ void k_ell2(const int* __restrict__ ell, const unsigned short* __restrict__ g2b,
                       float* __restrict__ out, int n_nodes) {
    int t = threadIdx.x;
    int lane = t & 63;
    int g = lane >> 3, fl = lane & 7;
    int node = blockIdx.x * 32 + (t >> 6) * 8 + g;
    if (node >= n_nodes) return;
    const int4* ep = (const int4*)(ell + (size_t)node * W_ELL);
    int4 i0 = ep[0], i1 = ep[1], i2 = ep[2], i3 = ep[3], i4 = ep[4];
    ushort4 su = ((const ushort4*)(g2b + (size_t)node * 32))[fl];
    float a0 = bf2f(su.x), a1 = bf2f(su.y), a2 = bf2f(su.z), a3 = bf2f(su.w);
    GATH32(i0.x) GATH32(i0.y) GATH32(i0.z) GATH32(i0.w)
    GATH32(i1.x) GATH32(i1.y) GATH32(i1.z) GATH32(i1.w)
    GATH32(i2.x) GATH32(i2.y) GATH32(i2.z) GATH32(i2.w)
    GATH32(i3.x) GATH32(i3.y) GATH32(i3.z) GATH32(i3.w)
    GATH32(i4.x) GATH32(i4.y) GATH32(i4.z) GATH32(i4.w)
    float4 o = make_float4(a0, a1, a2, a3);
    ((float4*)(out + (size_t)node * 32))[fl] = o;
}

// Overflow cleanup layer 2: fp32 atomics into out.
__global__ void k_oflow2(const int* __restrict__ ovf, const int* __restrict__ ovf_cnt,
                         const unsigned short* __restrict__ g2b, float* __restrict__ out) {
    int n = *ovf_cnt;
    int total = n * 8;
    for (int i = blockIdx.x * blockDim.x + threadIdx.x; i < total;
         i += gridDim.x * blockDim.x) {
        int e = i >> 3, fl = i & 7;
        int src = ovf[2 * e], dst = ovf[2 * e + 1];
        ushort4 u = ((const ushort4*)(g2b + (size_t)src * 32))[fl];
        float* op = out + (size_t)dst * 32 + fl * 4;
        atomicAdd(op + 0, bf2f(u.x));
        atomicAdd(op + 1, bf2f(u.y));
        atomicAdd(op + 2, bf2f(u.z));
        atomicAdd(op + 3, bf2f(u.w));
    }
}

// out = di*out + b2 (in place), float4.
__global__ void k_final(float* __restrict__ out, const float* __restrict__ dinv,
                        const float* __restrict__ b2, int n_nodes) {
    int i = blockIdx.x * TPB + threadIdx.x;
    if (i >= n_nodes * 8) return;
    int node = i >> 3, c = i & 7;
    float di = dinv[node];
    float4 v = ((float4*)out)[i];
    float4 b = ((const float4*)b2)[c];
    v.x = di * v.x + b.x;
    v.y = di * v.y + b.y;
    v.z = di * v.z + b.z;
    v.w = di * v.w + b.w;
    ((float4*)out)[i] = v;
}

extern "C" void kernel_launch(void* const* d_in, const int* in_sizes, int n_in,
                              void* d_out, int out_size, void* d_ws, size_t ws_size,
                              hipStream_t stream) {
    const float* x  = (const float*)d_in[0];
    const void*  ei = d_in[1];
    const float* W1 = (const float*)d_in[2];
    const float* b1 = (const float*)d_in[3];
    const float* W2 = (const float*)d_in[4];
    const float* b2 = (const float*)d_in[5];
    float* out = (float*)d_out;

    const int n_nodes = in_sizes[0] / 64;
    const int E = in_sizes[1] / 2;
    const int nb = (n_nodes + NPB - 1) / NPB;  // 196 (<= 256)

    char* p = (char*)d_ws;
    auto carve = [&](size_t bytes) {
        char* r = p;
        p += (bytes + 255) / 256 * 256;
        return r;
    };
    int* flag      = (int*)carve(sizeof(int));
    int* bucket_wp = (int*)carve(256 * sizeof(int));
    int* ovf_cnt   = (int*)carve(sizeof(int));
    int* cnt       = (int*)carve((size_t)n_nodes * sizeof(int));
    float* dinv    = (float*)carve((size_t)n_nodes * sizeof(float));
    unsigned int* gstage = (unsigned int*)carve((size_t)nb * BCAP * sizeof(unsigned int));
    int* ell       = (int*)carve((size_t)nb * NPB * W_ELL * sizeof(int));
    int* ovf       = (int*)carve((size_t)E * 2 * sizeof(int));
    unsigned short* g1b = (unsigned short*)carve(((size_t)n_nodes + 1) * 64 * sizeof(unsigned short));
    unsigned short* g2b = (unsigned short*)carve(((size_t)n_nodes + 1) * 32 * sizeof(unsigned short));
    float* h1f     = (float*)carve((size_t)n_nodes * 64 * sizeof(float));

    k_detect<<<1, TPB, 0, stream>>>((const unsigned int*)ei, in_sizes[1], flag, bucket_wp,
                                    ovf_cnt, g1b, g2b, n_nodes);
    k_binA<<<(E + TILE_E - 1) / TILE_E, TPB, 0, stream>>>(ei, flag, E, nb, gstage, bucket_wp);
    k_ellB<<<nb, 512, 0, stream>>>(gstage, bucket_wp, ell, cnt, ovf, ovf_cnt, n_nodes);
    k_gemm1<<<(n_nodes + 15) / 16, TPB, 0, stream>>>(x, W1, cnt, dinv, g1b, n_nodes);
    k_ell1<<<(n_nodes + 15) / 16, TPB, 0, stream>>>(ell, g1b, h1f, n_nodes);
    k_oflow1<<<64, TPB, 0, stream>>>(ovf, ovf_cnt, g1b, h1f);
    k_gemm2<<<(n_nodes + 15) / 16, TPB, 0, stream>>>(h1f, dinv, b1, W2, g2b, n_nodes);
    k_ell2<<<(n_nodes + 31) / 32, TPB, 0, stream>>>(ell, g2b, out, n_nodes);
    k_oflow2<<<64, TPB, 0, stream>>>(ovf, ovf_cnt, g2b, out);
    k_final<<<(n_nodes * 8 + TPB - 1) / TPB, TPB, 0, stream>>>(out, dinv, b2, n_nodes);
}

// Round 9
// 142.690 us; speedup vs baseline: 6.1348x; 1.2268x over previous
//
#include <hip/hip_runtime.h>

// 2-layer GCN, ELL pull aggregation + MFMA dense GEMMs (bf16 in, fp32 acc).
// detect (+W1/W2 bf16 transpose) -> binA -> ellB -> gemm1(MFMA) -> ell1
//  -> oflow1 -> gemm2(MFMA) -> ell2 -> oflow2 -> final

#define TPB 256
#define NPB 512     // nodes per bucket (dst >> 9)
#define BCAP 8192   // max edges per bucket (mean ~6122)
#define TILE_E 2048 // edges per binning block
#define W_ELL 20    // ELL width (Poisson(12): ~2% rows overflow)

typedef __attribute__((ext_vector_type(8))) short bf16x8;
typedef __attribute__((ext_vector_type(4))) float f32x4;

__device__ __forceinline__ float bf2f(unsigned short u) {
    unsigned int v = ((unsigned int)u) << 16;
    return __builtin_bit_cast(float, v);
}
__device__ __forceinline__ unsigned short f2bf(float f) {
    unsigned int u = __builtin_bit_cast(unsigned int, f);
    u += 0x7FFFu + ((u >> 16) & 1u);  // RNE
    return (unsigned short)(u >> 16);
}
__device__ __forceinline__ int edge_val(const void* ei, int is64, long long idx) {
    if (is64) return (int)((const long long*)ei)[idx];
    return ((const int*)ei)[idx];
}

// detect int64 vs int32; zero bucket_wp/ovf_cnt/zero-rows; build bf16 W^T tables.
__global__ void k_detect(const unsigned int* __restrict__ w, int nelems, int* flag,
                         int* __restrict__ bucket_wp, int* __restrict__ ovf_cnt,
                         unsigned short* __restrict__ g1b, unsigned short* __restrict__ g2b,
                         int n_nodes, const float* __restrict__ W1, const float* __restrict__ W2,
                         unsigned short* __restrict__ W1Tb, unsigned short* __restrict__ W2Tb) {
    __shared__ unsigned int red[TPB];
    __shared__ float tr[64][65];
    int t = threadIdx.x;
    bucket_wp[t] = 0;
    if (t == 0) *ovf_cnt = 0;
    if (t < 64) g1b[(size_t)n_nodes * 64 + t] = 0;
    if (t < 32) g2b[(size_t)n_nodes * 32 + t] = 0;
    // W1 (64x64 [k][f]) -> W1Tb (64x64 [f][k] bf16)
    for (int i = t; i < 4096; i += TPB) tr[i >> 6][i & 63] = W1[i];
    __syncthreads();
    for (int i = t; i < 4096; i += TPB) {
        int f = i >> 6, k = i & 63;
        W1Tb[i] = f2bf(tr[k][f]);
    }
    __syncthreads();
    // W2 (64x32 [k][f]) -> W2Tb (32x64 [f][k] bf16)
    for (int i = t; i < 2048; i += TPB) tr[i >> 5][i & 31] = W2[i];
    __syncthreads();
    for (int i = t; i < 2048; i += TPB) {
        int f = i >> 6, k = i & 63;
        W2Tb[i] = f2bf(tr[k][f]);
    }
    // int64 detect
    unsigned int acc = 0;
    int limit = nelems < 16384 ? nelems : 16384;
    for (int i = 1 + 2 * t; i < limit; i += 2 * TPB) acc |= w[i];
    red[t] = acc;
    __syncthreads();
    for (int s = TPB / 2; s > 0; s >>= 1) {
        if (t < s) red[t] |= red[t + s];
        __syncthreads();
    }
    if (t == 0) *flag = (red[0] == 0u) ? 1 : 0;
}

// Pass A: bin edges by bucket = dst>>9 into gstage (bucket-major, BCAP stride).
__launch_bounds__(TPB)
__global__ void k_binA(const void* __restrict__ ei, const int* __restrict__ flag, int E,
                       int nb, unsigned int* __restrict__ gstage, int* __restrict__ bucket_wp) {
    __shared__ int lcnt[256];
    __shared__ int lboff[256];
    __shared__ int lrank[256];
    __shared__ int gbase[256];
    __shared__ int sh[256];
    __shared__ unsigned int spair[TILE_E];
    __shared__ unsigned char sbuck[TILE_E];
    int is64 = *flag;
    int t = threadIdx.x;
    int base_e = blockIdx.x * TILE_E;
    int ne = E - base_e;
    if (ne > TILE_E) ne = TILE_E;

    lcnt[t] = 0;
    lrank[t] = 0;
    __syncthreads();

    int myb[8];
    unsigned int mypair[8];
#pragma unroll
    for (int k = 0; k < 8; ++k) {
        int idx = t + k * TPB;
        myb[k] = -1;
        if (idx < ne) {
            long long e = base_e + idx;
            int s = edge_val(ei, is64, e);
            int d = edge_val(ei, is64, (long long)E + e);
            int b = d >> 9;
            myb[k] = b;
            mypair[k] = (unsigned int)s | ((unsigned int)(d & (NPB - 1)) << 20);
            atomicAdd(&lcnt[b], 1);
        }
    }
    __syncthreads();

    int v0 = lcnt[t];
    sh[t] = v0;
    __syncthreads();
    for (int st = 1; st < TPB; st <<= 1) {
        int u = (t >= st) ? sh[t - st] : 0;
        __syncthreads();
        sh[t] += u;
        __syncthreads();
    }
    lboff[t] = sh[t] - v0;
    if (t < nb && v0 > 0) gbase[t] = atomicAdd(&bucket_wp[t], v0);
    __syncthreads();

#pragma unroll
    for (int k = 0; k < 8; ++k) {
        int b = myb[k];
        if (b >= 0) {
            int r = atomicAdd(&lrank[b], 1);
            int slot = lboff[b] + r;
            spair[slot] = mypair[k];
            sbuck[slot] = (unsigned char)b;
        }
    }
    __syncthreads();

    for (int j = t; j < ne; j += TPB) {
        int b = sbuck[j];
        int pos = gbase[b] + (j - lboff[b]);
        if (pos < BCAP) gstage[(size_t)b * BCAP + pos] = spair[j];
    }
}

// Per bucket: build ELL slab (512 nodes x 20) in LDS, overflow to global list.
__launch_bounds__(512)
__global__ void k_ellB(const unsigned int* __restrict__ gstage, const int* __restrict__ bucket_wp,
                       int* __restrict__ ell, int* __restrict__ cnt, int* __restrict__ ovf,
                       int* __restrict__ ovf_cnt, int n_nodes) {
    __shared__ int lrank[NPB];
    __shared__ int slab[NPB * W_ELL];  // 40 KB
    int b = blockIdx.x, t = threadIdx.x;
    int zr = n_nodes;
    lrank[t] = 0;
    for (int j = t; j < NPB * W_ELL; j += 512) slab[j] = zr;
    __syncthreads();
    int cb = bucket_wp[b];
    if (cb > BCAP) cb = BCAP;
    const unsigned int* gp = gstage + (size_t)b * BCAP;
    for (int j = t; j < cb; j += 512) {
        unsigned int w = gp[j];
        int dl = (int)(w >> 20);
        int src = (int)(w & 0xFFFFFu);
        int r = atomicAdd(&lrank[dl], 1);
        if (r < W_ELL) {
            slab[dl * W_ELL + r] = src;
        } else {
            int o = atomicAdd(ovf_cnt, 1);
            ovf[2 * o] = src;
            ovf[2 * o + 1] = b * NPB + dl;
        }
    }
    __syncthreads();
    int node = b * NPB + t;
    if (node < n_nodes) cnt[node] = lrank[t];
    for (int j = t; j < NPB * W_ELL; j += 512) ell[(size_t)b * (NPB * W_ELL) + j] = slab[j];
}

// MFMA gemm1: g1b = bf16((x@W1)*dinv). Wave = 16-node tile; 4 feature-tiles.
// A-frag: row=lane&15, k=8*(lane>>4)+j. B-frag from W1Tb[f][k] (=W1^T).
// D: row=4*(lane>>4)+reg, col=lane&15 [m89-verified].
__launch_bounds__(TPB)
__global__ void k_gemm1(const float* __restrict__ x, const unsigned short* __restrict__ W1Tb,
                        const int* __restrict__ cnt, float* __restrict__ dinv,
                        unsigned short* __restrict__ g1b, int n_nodes) {
    int t = threadIdx.x;
    int w = t >> 6, lane = t & 63;
    int r = lane & 15, kb = lane >> 4;
    int nb = (blockIdx.x * 4 + w) * 16;
    if (nb >= n_nodes) return;
    int ar = nb + r;
    if (ar > n_nodes - 1) ar = n_nodes - 1;
    const float* xp = x + (size_t)ar * 64 + kb * 8;
    float4 v0 = ((const float4*)xp)[0];
    float4 v1 = ((const float4*)xp)[1];
    float4 v2 = ((const float4*)(xp + 32))[0];
    float4 v3 = ((const float4*)(xp + 32))[1];
    union { bf16x8 v; unsigned short e[8]; } a0, a1;
    a0.e[0] = f2bf(v0.x); a0.e[1] = f2bf(v0.y); a0.e[2] = f2bf(v0.z); a0.e[3] = f2bf(v0.w);
    a0.e[4] = f2bf(v1.x); a0.e[5] = f2bf(v1.y); a0.e[6] = f2bf(v1.z); a0.e[7] = f2bf(v1.w);
    a1.e[0] = f2bf(v2.x); a1.e[1] = f2bf(v2.y); a1.e[2] = f2bf(v2.z); a1.e[3] = f2bf(v2.w);
    a1.e[4] = f2bf(v3.x); a1.e[5] = f2bf(v3.y); a1.e[6] = f2bf(v3.z); a1.e[7] = f2bf(v3.w);

    int rnode = nb + 4 * kb;
    float d[4];
    bool full = (nb + 16 <= n_nodes);
    if (full) {
        int4 c4 = *(const int4*)(cnt + rnode);
        d[0] = rsqrtf((float)(c4.x + 1));
        d[1] = rsqrtf((float)(c4.y + 1));
        d[2] = rsqrtf((float)(c4.z + 1));
        d[3] = rsqrtf((float)(c4.w + 1));
        if (r == 0) *(float4*)(dinv + rnode) = make_float4(d[0], d[1], d[2], d[3]);
    } else {
#pragma unroll
        for (int j = 0; j < 4; ++j) {
            int n2 = rnode + j;
            d[j] = (n2 < n_nodes) ? rsqrtf((float)(cnt[n2] + 1)) : 0.f;
            if (r == 0 && n2 < n_nodes) dinv[n2] = d[j];
        }
    }

#pragma unroll
    for (int ft = 0; ft < 4; ++ft) {
        const unsigned short* bp = W1Tb + (size_t)(ft * 16 + r) * 64 + kb * 8;
        bf16x8 b0 = *(const bf16x8*)bp;
        bf16x8 b1v = *(const bf16x8*)(bp + 32);
        f32x4 acc = {0.f, 0.f, 0.f, 0.f};
        acc = __builtin_amdgcn_mfma_f32_16x16x32_bf16(a0.v, b0, acc, 0, 0, 0);
        acc = __builtin_amdgcn_mfma_f32_16x16x32_bf16(a1.v, b1v, acc, 0, 0, 0);
#pragma unroll
        for (int j = 0; j < 4; ++j) {
            int n2 = rnode + j;
            if (n2 < n_nodes) g1b[(size_t)n2 * 64 + ft * 16 + r] = f2bf(acc[j] * d[j]);
        }
    }
}

#define GATH64(S)                                                              \
    {                                                                          \
        ushort4 u = ((const ushort4*)(g1b + (size_t)(S) * 64))[fl];            \
        a0 += bf2f(u.x); a1 += bf2f(u.y); a2 += bf2f(u.z); a3 += bf2f(u.w);    \
    }

// Layer-1 ELL pull: 16-lane group per node, 20 branchless gathers in flight.
__launch_bounds__(TPB)
__global__ void k_ell1(const int* __restrict__ ell, const unsigned short* __restrict__ g1b,
                       float* __restrict__ h1f, int n_nodes) {
    int t = threadIdx.x;
    int lane = t & 63;
    int g = lane >> 4, fl = lane & 15;
    int node = blockIdx.x * 16 + (t >> 6) * 4 + g;
    if (node >= n_nodes) return;
    const int4* ep = (const int4*)(ell + (size_t)node * W_ELL);
    int4 i0 = ep[0], i1 = ep[1], i2 = ep[2], i3 = ep[3], i4 = ep[4];
    ushort4 su = ((const ushort4*)(g1b + (size_t)node * 64))[fl];
    float a0 = bf2f(su.x), a1 = bf2f(su.y), a2 = bf2f(su.z), a3 = bf2f(su.w);
    GATH64(i0.x) GATH64(i0.y) GATH64(i0.z) GATH64(i0.w)
    GATH64(i1.x) GATH64(i1.y) GATH64(i1.z) GATH64(i1.w)
    GATH64(i2.x) GATH64(i2.y) GATH64(i2.z) GATH64(i2.w)
    GATH64(i3.x) GATH64(i3.y) GATH64(i3.z) GATH64(i3.w)
    GATH64(i4.x) GATH64(i4.y) GATH64(i4.z) GATH64(i4.w)
    float4 o = make_float4(a0, a1, a2, a3);
    ((float4*)(h1f + (size_t)node * 64))[fl] = o;
}

// Overflow cleanup layer 1: fp32 atomics into h1f.
__global__ void k_oflow1(const int* __restrict__ ovf, const int* __restrict__ ovf_cnt,
                         const unsigned short* __restrict__ g1b, float* __restrict__ h1f) {
    int n = *ovf_cnt;
    int total = n * 16;
    for (int i = blockIdx.x * blockDim.x + threadIdx.x; i < total;
         i += gridDim.x * blockDim.x) {
        int e = i >> 4, fl = i & 15;
        int src = ovf[2 * e], dst = ovf[2 * e + 1];
        ushort4 u = ((const ushort4*)(g1b + (size_t)src * 64))[fl];
        float* hp = h1f + (size_t)dst * 64 + fl * 4;
        atomicAdd(hp + 0, bf2f(u.x));
        atomicAdd(hp + 1, bf2f(u.y));
        atomicAdd(hp + 2, bf2f(u.z));
        atomicAdd(hp + 3, bf2f(u.w));
    }
}

// MFMA gemm2: g2b = bf16(((di*h1f + b1)@W2)*di). Wave = 16-node tile; 2 ft.
__launch_bounds__(TPB)
__global__ void k_gemm2(const float* __restrict__ h1f, const float* __restrict__ dinv,
                        const float* __restrict__ b1, const unsigned short* __restrict__ W2Tb,
                        unsigned short* __restrict__ g2b, int n_nodes) {
    int t = threadIdx.x;
    int w = t >> 6, lane = t & 63;
    int r = lane & 15, kb = lane >> 4;
    int nb = (blockIdx.x * 4 + w) * 16;
    if (nb >= n_nodes) return;
    int ar = nb + r;
    if (ar > n_nodes - 1) ar = n_nodes - 1;
    float di_a = dinv[ar];
    const float* bp1 = b1 + kb * 8;
    float4 p0 = ((const float4*)bp1)[0];
    float4 p1 = ((const float4*)bp1)[1];
    float4 q0 = ((const float4*)(bp1 + 32))[0];
    float4 q1 = ((const float4*)(bp1 + 32))[1];
    const float* hp = h1f + (size_t)ar * 64 + kb * 8;
    float4 v0 = ((const float4*)hp)[0];
    float4 v1 = ((const float4*)hp)[1];
    float4 v2 = ((const float4*)(hp + 32))[0];
    float4 v3 = ((const float4*)(hp + 32))[1];
    union { bf16x8 v; unsigned short e[8]; } a0, a1;
    a0.e[0] = f2bf(di_a * v0.x + p0.x); a0.e[1] = f2bf(di_a * v0.y + p0.y);
    a0.e[2] = f2bf(di_a * v0.z + p0.z); a0.e[3] = f2bf(di_a * v0.w + p0.w);
    a0.e[4] = f2bf(di_a * v1.x + p1.x); a0.e[5] = f2bf(di_a * v1.y + p1.y);
    a0.e[6] = f2bf(di_a * v1.z + p1.z); a0.e[7] = f2bf(di_a * v1.w + p1.w);
    a1.e[0] = f2bf(di_a * v2.x + q0.x); a1.e[1] = f2bf(di_a * v2.y + q0.y);
    a1.e[2] = f2bf(di_a * v2.z + q0.z); a1.e[3] = f2bf(di_a * v2.w + q0.w);
    a1.e[4] = f2bf(di_a * v3.x + q1.x); a1.e[5] = f2bf(di_a * v3.y + q1.y);
    a1.e[6] = f2bf(di_a * v3.z + q1.z); a1.e[7] = f2bf(di_a * v3.w + q1.w);

    int rnode = nb + 4 * kb;
    float d[4];
    bool full = (nb + 16 <= n_nodes);
    if (full) {
        float4 d4 = *(const float4*)(dinv + rnode);
        d[0] = d4.x; d[1] = d4.y; d[2] = d4.z; d[3] = d4.w;
    } else {
#pragma unroll
        for (int j = 0; j < 4; ++j) {
            int n2 = rnode + j;
            d[j] = (n2 < n_nodes) ? dinv[n2] : 0.f;
        }
    }

#pragma unroll
    for (int ft = 0; ft < 2; ++ft) {
        const unsigned short* wp = W2Tb + (size_t)(ft * 16 + r) * 64 + kb * 8;
        bf16x8 b0 = *(const bf16x8*)wp;
        bf16x8 b1v = *(const bf16x8*)(wp + 32);
        f32x4 acc = {0.f, 0.f, 0.f, 0.f};
        acc = __builtin_amdgcn_mfma_f32_16x16x32_bf16(a0.v, b0, acc, 0, 0, 0);
        acc = __builtin_amdgcn_mfma_f32_16x16x32_bf16(a1.v, b1v, acc, 0, 0, 0);
#pragma unroll
        for (int j = 0; j < 4; ++j) {
            int n2 = rnode + j;
            if (n2 < n_nodes) g2b[(size_t)n2 * 32 + ft * 16 + r] = f2bf(acc[j] * d[j]);
        }
    }
}

#define GATH32(S)                                                              \
    {                                                                          \
        ushort4 u = ((const ushort4*)(g2b + (size_t)(S) * 32))[fl];            \
        a0 += bf2f(u.x); a1 += bf2f(u.y); a2 += bf2f(u.z); a3 += bf2f(u.w);    \
    }

// Layer-2 ELL pull: 8-lane group per node. out = raw fp32 sum (pre-scale).
__launch_bounds__(TPB)
__global__ void k_ell2(const int* __restrict__ ell, const unsigned short* __restrict__ g2b,
                       float* __restrict__ out, int n_nodes) {
    int t = threadIdx.x;
    int lane = t & 63;
    int g = lane >> 3, fl = lane & 7;
    int node = blockIdx.x * 32 + (t >> 6) * 8 + g;
    if (node >= n_nodes) return;
    const int4* ep = (const int4*)(ell + (size_t)node * W_ELL);
    int4 i0 = ep[0], i1 = ep[1], i2 = ep[2], i3 = ep[3], i4 = ep[4];
    ushort4 su = ((const ushort4*)(g2b + (size_t)node * 32))[fl];
    float a0 = bf2f(su.x), a1 = bf2f(su.y), a2 = bf2f(su.z), a3 = bf2f(su.w);
    GATH32(i0.x) GATH32(i0.y) GATH32(i0.z) GATH32(i0.w)
    GATH32(i1.x) GATH32(i1.y) GATH32(i1.z) GATH32(i1.w)
    GATH32(i2.x) GATH32(i2.y) GATH32(i2.z) GATH32(i2.w)
    GATH32(i3.x) GATH32(i3.y) GATH32(i3.z) GATH32(i3.w)
    GATH32(i4.x) GATH32(i4.y) GATH32(i4.z) GATH32(i4.w)
    float4 o = make_float4(a0, a1, a2, a3);
    ((float4*)(out + (size_t)node * 32))[fl] = o;
}

// Overflow cleanup layer 2: fp32 atomics into out.
__global__ void k_oflow2(const int* __restrict__ ovf, const int* __restrict__ ovf_cnt,
                         const unsigned short* __restrict__ g2b, float* __restrict__ out) {
    int n = *ovf_cnt;
    int total = n * 8;
    for (int i = blockIdx.x * blockDim.x + threadIdx.x; i < total;
         i += gridDim.x * blockDim.x) {
        int e = i >> 3, fl = i & 7;
        int src = ovf[2 * e], dst = ovf[2 * e + 1];
        ushort4 u = ((const ushort4*)(g2b + (size_t)src * 32))[fl];
        float* op = out + (size_t)dst * 32 + fl * 4;
        atomicAdd(op + 0, bf2f(u.x));
        atomicAdd(op + 1, bf2f(u.y));
        atomicAdd(op + 2, bf2f(u.z));
        atomicAdd(op + 3, bf2f(u.w));
    }
}

// out = di*out + b2 (in place), float4.
__global__ void k_final(float* __restrict__ out, const float* __restrict__ dinv,
                        const float* __restrict__ b2, int n_nodes) {
    int i = blockIdx.x * TPB + threadIdx.x;
    if (i >= n_nodes * 8) return;
    int node = i >> 3, c = i & 7;
    float di = dinv[node];
    float4 v = ((float4*)out)[i];
    float4 b = ((const float4*)b2)[c];
    v.x = di * v.x + b.x;
    v.y = di * v.y + b.y;
    v.z = di * v.z + b.z;
    v.w = di * v.w + b.w;
    ((float4*)out)[i] = v;
}

extern "C" void kernel_launch(void* const* d_in, const int* in_sizes, int n_in,
                              void* d_out, int out_size, void* d_ws, size_t ws_size,
                              hipStream_t stream) {
    const float* x  = (const float*)d_in[0];
    const void*  ei = d_in[1];
    const float* W1 = (const float*)d_in[2];
    const float* b1 = (const float*)d_in[3];
    const float* W2 = (const float*)d_in[4];
    const float* b2 = (const float*)d_in[5];
    float* out = (float*)d_out;

    const int n_nodes = in_sizes[0] / 64;
    const int E = in_sizes[1] / 2;
    const int nb = (n_nodes + NPB - 1) / NPB;  // 196 (<= 256)

    char* p = (char*)d_ws;
    auto carve = [&](size_t bytes) {
        char* r = p;
        p += (bytes + 255) / 256 * 256;
        return r;
    };
    int* flag      = (int*)carve(sizeof(int));
    int* bucket_wp = (int*)carve(256 * sizeof(int));
    int* ovf_cnt   = (int*)carve(sizeof(int));
    int* cnt       = (int*)carve((size_t)n_nodes * sizeof(int));
    float* dinv    = (float*)carve((size_t)n_nodes * sizeof(float));
    unsigned int* gstage = (unsigned int*)carve((size_t)nb * BCAP * sizeof(unsigned int));
    int* ell       = (int*)carve((size_t)nb * NPB * W_ELL * sizeof(int));
    int* ovf       = (int*)carve((size_t)E * 2 * sizeof(int));
    unsigned short* g1b = (unsigned short*)carve(((size_t)n_nodes + 1) * 64 * sizeof(unsigned short));
    unsigned short* g2b = (unsigned short*)carve(((size_t)n_nodes + 1) * 32 * sizeof(unsigned short));
    float* h1f     = (float*)carve((size_t)n_nodes * 64 * sizeof(float));
    unsigned short* W1Tb = (unsigned short*)carve(64 * 64 * sizeof(unsigned short));
    unsigned short* W2Tb = (unsigned short*)carve(32 * 64 * sizeof(unsigned short));

    k_detect<<<1, TPB, 0, stream>>>((const unsigned int*)ei, in_sizes[1], flag, bucket_wp,
                                    ovf_cnt, g1b, g2b, n_nodes, W1, W2, W1Tb, W2Tb);
    k_binA<<<(E + TILE_E - 1) / TILE_E, TPB, 0, stream>>>(ei, flag, E, nb, gstage, bucket_wp);
    k_ellB<<<nb, 512, 0, stream>>>(gstage, bucket_wp, ell, cnt, ovf, ovf_cnt, n_nodes);
    k_gemm1<<<(n_nodes + 63) / 64, TPB, 0, stream>>>(x, W1Tb, cnt, dinv, g1b, n_nodes);
    k_ell1<<<(n_nodes + 15) / 16, TPB, 0, stream>>>(ell, g1b, h1f, n_nodes);
    k_oflow1<<<64, TPB, 0, stream>>>(ovf, ovf_cnt, g1b, h1f);
    k_gemm2<<<(n_nodes + 63) / 64, TPB, 0, stream>>>(h1f, dinv, b1, W2Tb, g2b, n_nodes);
    k_ell2<<<(n_nodes + 31) / 32, TPB, 0, stream>>>(ell, g2b, out, n_nodes);
    k_oflow2<<<64, TPB, 0, stream>>>(ovf, ovf_cnt, g2b, out);
    k_final<<<(n_nodes * 8 + TPB - 1) / TPB, TPB, 0, stream>>>(out, dinv, b2, n_nodes);
}

// Round 10
// 134.224 us; speedup vs baseline: 6.5217x; 1.0631x over previous
//
#include <hip/hip_runtime.h>

// 2-layer GCN: ELL pull + MFMA GEMMs, fused layer1-pull+layer2-GEMM.
// detect (+W^T bf16) -> binA -> ellB (+ovfacc zero) -> gemm1(MFMA)
//  -> oflow1 (ovf sums -> ovfacc) -> fused1 (gather + di*raw+b1 -> LDS -> MFMA -> g2b)
//  -> ell2 (gather + di*sum+b2 -> out) -> oflow2 (scaled atomics)

#define TPB 256
#define NPB 512     // nodes per bucket (dst >> 9)
#define BCAP 8192   // max edges per bucket (mean ~6122)
#define TILE_E 2048 // edges per binning block
#define W_ELL 20    // ELL width (Poisson(12): ~1% rows overflow)

typedef __attribute__((ext_vector_type(8))) short bf16x8;
typedef __attribute__((ext_vector_type(4))) float f32x4;

__device__ __forceinline__ float bf2f(unsigned short u) {
    unsigned int v = ((unsigned int)u) << 16;
    return __builtin_bit_cast(float, v);
}
__device__ __forceinline__ unsigned short f2bf(float f) {
    unsigned int u = __builtin_bit_cast(unsigned int, f);
    u += 0x7FFFu + ((u >> 16) & 1u);  // RNE
    return (unsigned short)(u >> 16);
}
__device__ __forceinline__ int edge_val(const void* ei, int is64, long long idx) {
    if (is64) return (int)((const long long*)ei)[idx];
    return ((const int*)ei)[idx];
}

// detect int64 vs int32; zero bucket_wp/ovf_cnt/zero-rows; build bf16 W^T tables.
__global__ void k_detect(const unsigned int* __restrict__ w, int nelems, int* flag,
                         int* __restrict__ bucket_wp, int* __restrict__ ovf_cnt,
                         unsigned short* __restrict__ g1b, unsigned short* __restrict__ g2b,
                         int n_nodes, const float* __restrict__ W1, const float* __restrict__ W2,
                         unsigned short* __restrict__ W1Tb, unsigned short* __restrict__ W2Tb) {
    __shared__ unsigned int red[TPB];
    __shared__ float tr[64][65];
    int t = threadIdx.x;
    bucket_wp[t] = 0;
    if (t == 0) *ovf_cnt = 0;
    if (t < 64) g1b[(size_t)n_nodes * 64 + t] = 0;
    if (t < 32) g2b[(size_t)n_nodes * 32 + t] = 0;
    // W1 (64x64 [k][f]) -> W1Tb (64x64 [f][k] bf16)
    for (int i = t; i < 4096; i += TPB) tr[i >> 6][i & 63] = W1[i];
    __syncthreads();
    for (int i = t; i < 4096; i += TPB) {
        int f = i >> 6, k = i & 63;
        W1Tb[i] = f2bf(tr[k][f]);
    }
    __syncthreads();
    // W2 (64x32 [k][f]) -> W2Tb (32x64 [f][k] bf16)
    for (int i = t; i < 2048; i += TPB) tr[i >> 5][i & 31] = W2[i];
    __syncthreads();
    for (int i = t; i < 2048; i += TPB) {
        int f = i >> 6, k = i & 63;
        W2Tb[i] = f2bf(tr[k][f]);
    }
    // int64 detect
    unsigned int acc = 0;
    int limit = nelems < 16384 ? nelems : 16384;
    for (int i = 1 + 2 * t; i < limit; i += 2 * TPB) acc |= w[i];
    red[t] = acc;
    __syncthreads();
    for (int s = TPB / 2; s > 0; s >>= 1) {
        if (t < s) red[t] |= red[t + s];
        __syncthreads();
    }
    if (t == 0) *flag = (red[0] == 0u) ? 1 : 0;
}

// Pass A: bin edges by bucket = dst>>9 into gstage (bucket-major, BCAP stride).
__launch_bounds__(TPB)
__global__ void k_binA(const void* __restrict__ ei, const int* __restrict__ flag, int E,
                       int nb, unsigned int* __restrict__ gstage, int* __restrict__ bucket_wp) {
    __shared__ int lcnt[256];
    __shared__ int lboff[256];
    __shared__ int lrank[256];
    __shared__ int gbase[256];
    __shared__ int sh[256];
    __shared__ unsigned int spair[TILE_E];
    __shared__ unsigned char sbuck[TILE_E];
    int is64 = *flag;
    int t = threadIdx.x;
    int base_e = blockIdx.x * TILE_E;
    int ne = E - base_e;
    if (ne > TILE_E) ne = TILE_E;

    lcnt[t] = 0;
    lrank[t] = 0;
    __syncthreads();

    int myb[8];
    unsigned int mypair[8];
#pragma unroll
    for (int k = 0; k < 8; ++k) {
        int idx = t + k * TPB;
        myb[k] = -1;
        if (idx < ne) {
            long long e = base_e + idx;
            int s = edge_val(ei, is64, e);
            int d = edge_val(ei, is64, (long long)E + e);
            int b = d >> 9;
            myb[k] = b;
            mypair[k] = (unsigned int)s | ((unsigned int)(d & (NPB - 1)) << 20);
            atomicAdd(&lcnt[b], 1);
        }
    }
    __syncthreads();

    int v0 = lcnt[t];
    sh[t] = v0;
    __syncthreads();
    for (int st = 1; st < TPB; st <<= 1) {
        int u = (t >= st) ? sh[t - st] : 0;
        __syncthreads();
        sh[t] += u;
        __syncthreads();
    }
    lboff[t] = sh[t] - v0;
    if (t < nb && v0 > 0) gbase[t] = atomicAdd(&bucket_wp[t], v0);
    __syncthreads();

#pragma unroll
    for (int k = 0; k < 8; ++k) {
        int b = myb[k];
        if (b >= 0) {
            int r = atomicAdd(&lrank[b], 1);
            int slot = lboff[b] + r;
            spair[slot] = mypair[k];
            sbuck[slot] = (unsigned char)b;
        }
    }
    __syncthreads();

    for (int j = t; j < ne; j += TPB) {
        int b = sbuck[j];
        int pos = gbase[b] + (j - lboff[b]);
        if (pos < BCAP) gstage[(size_t)b * BCAP + pos] = spair[j];
    }
}

// Per bucket: build ELL slab (512 x 20) in LDS, overflow to list + zero ovfacc rows.
__launch_bounds__(512)
__global__ void k_ellB(const unsigned int* __restrict__ gstage, const int* __restrict__ bucket_wp,
                       int* __restrict__ ell, int* __restrict__ cnt, int* __restrict__ ovf,
                       int* __restrict__ ovf_cnt, float* __restrict__ ovfacc, int n_nodes) {
    __shared__ int lrank[NPB];
    __shared__ int slab[NPB * W_ELL];  // 40 KB
    int b = blockIdx.x, t = threadIdx.x;
    int zr = n_nodes;
    lrank[t] = 0;
    for (int j = t; j < NPB * W_ELL; j += 512) slab[j] = zr;
    __syncthreads();
    int cb = bucket_wp[b];
    if (cb > BCAP) cb = BCAP;
    const unsigned int* gp = gstage + (size_t)b * BCAP;
    for (int j = t; j < cb; j += 512) {
        unsigned int w = gp[j];
        int dl = (int)(w >> 20);
        int src = (int)(w & 0xFFFFFu);
        int r = atomicAdd(&lrank[dl], 1);
        if (r < W_ELL) {
            slab[dl * W_ELL + r] = src;
        } else {
            int o = atomicAdd(ovf_cnt, 1);
            ovf[2 * o] = src;
            ovf[2 * o + 1] = b * NPB + dl;
        }
    }
    __syncthreads();
    int node = b * NPB + t;
    if (node < n_nodes) {
        cnt[node] = lrank[t];
        if (lrank[t] > W_ELL) {  // zero this node's overflow accumulator row
            float4 z = make_float4(0.f, 0.f, 0.f, 0.f);
            float4* zp = (float4*)(ovfacc + (size_t)node * 64);
#pragma unroll
            for (int j = 0; j < 16; ++j) zp[j] = z;
        }
    }
    for (int j = t; j < NPB * W_ELL; j += 512) ell[(size_t)b * (NPB * W_ELL) + j] = slab[j];
}

// MFMA gemm1: g1b = bf16((x@W1)*dinv). Wave = 16-node tile; 4 feature-tiles.
__launch_bounds__(TPB)
__global__ void k_gemm1(const float* __restrict__ x, const unsigned short* __restrict__ W1Tb,
                        const int* __restrict__ cnt, float* __restrict__ dinv,
                        unsigned short* __restrict__ g1b, int n_nodes) {
    int t = threadIdx.x;
    int w = t >> 6, lane = t & 63;
    int r = lane & 15, kb = lane >> 4;
    int nb = (blockIdx.x * 4 + w) * 16;
    if (nb >= n_nodes) return;
    int ar = nb + r;
    if (ar > n_nodes - 1) ar = n_nodes - 1;
    const float* xp = x + (size_t)ar * 64 + kb * 8;
    float4 v0 = ((const float4*)xp)[0];
    float4 v1 = ((const float4*)xp)[1];
    float4 v2 = ((const float4*)(xp + 32))[0];
    float4 v3 = ((const float4*)(xp + 32))[1];
    union { bf16x8 v; unsigned short e[8]; } a0, a1;
    a0.e[0] = f2bf(v0.x); a0.e[1] = f2bf(v0.y); a0.e[2] = f2bf(v0.z); a0.e[3] = f2bf(v0.w);
    a0.e[4] = f2bf(v1.x); a0.e[5] = f2bf(v1.y); a0.e[6] = f2bf(v1.z); a0.e[7] = f2bf(v1.w);
    a1.e[0] = f2bf(v2.x); a1.e[1] = f2bf(v2.y); a1.e[2] = f2bf(v2.z); a1.e[3] = f2bf(v2.w);
    a1.e[4] = f2bf(v3.x); a1.e[5] = f2bf(v3.y); a1.e[6] = f2bf(v3.z); a1.e[7] = f2bf(v3.w);

    int rnode = nb + 4 * kb;
    float d[4];
    bool full = (nb + 16 <= n_nodes);
    if (full) {
        int4 c4 = *(const int4*)(cnt + rnode);
        d[0] = rsqrtf((float)(c4.x + 1));
        d[1] = rsqrtf((float)(c4.y + 1));
        d[2] = rsqrtf((float)(c4.z + 1));
        d[3] = rsqrtf((float)(c4.w + 1));
        if (r == 0) *(float4*)(dinv + rnode) = make_float4(d[0], d[1], d[2], d[3]);
    } else {
#pragma unroll
        for (int j = 0; j < 4; ++j) {
            int n2 = rnode + j;
            d[j] = (n2 < n_nodes) ? rsqrtf((float)(cnt[n2] + 1)) : 0.f;
            if (r == 0 && n2 < n_nodes) dinv[n2] = d[j];
        }
    }

#pragma unroll
    for (int ft = 0; ft < 4; ++ft) {
        const unsigned short* bp = W1Tb + (size_t)(ft * 16 + r) * 64 + kb * 8;
        bf16x8 b0 = *(const bf16x8*)bp;
        bf16x8 b1v = *(const bf16x8*)(bp + 32);
        f32x4 acc = {0.f, 0.f, 0.f, 0.f};
        acc = __builtin_amdgcn_mfma_f32_16x16x32_bf16(a0.v, b0, acc, 0, 0, 0);
        acc = __builtin_amdgcn_mfma_f32_16x16x32_bf16(a1.v, b1v, acc, 0, 0, 0);
#pragma unroll
        for (int j = 0; j < 4; ++j) {
            int n2 = rnode + j;
            if (n2 < n_nodes) g1b[(size_t)n2 * 64 + ft * 16 + r] = f2bf(acc[j] * d[j]);
        }
    }
}

// Overflow layer 1: raw fp32 atomics into ovfacc (rows pre-zeroed by ellB).
__global__ void k_oflow1(const int* __restrict__ ovf, const int* __restrict__ ovf_cnt,
                         const unsigned short* __restrict__ g1b, float* __restrict__ ovfacc) {
    int n = *ovf_cnt;
    int total = n * 16;
    for (int i = blockIdx.x * blockDim.x + threadIdx.x; i < total;
         i += gridDim.x * blockDim.x) {
        int e = i >> 4, fl = i & 15;
        int src = ovf[2 * e], dst = ovf[2 * e + 1];
        ushort4 u = ((const ushort4*)(g1b + (size_t)src * 64))[fl];
        float* hp = ovfacc + (size_t)dst * 64 + fl * 4;
        atomicAdd(hp + 0, bf2f(u.x));
        atomicAdd(hp + 1, bf2f(u.y));
        atomicAdd(hp + 2, bf2f(u.z));
        atomicAdd(hp + 3, bf2f(u.w));
    }
}

#define GATH64(S)                                                              \
    {                                                                          \
        ushort4 u = ((const ushort4*)(g1b + (size_t)(S) * 64))[fl];            \
        a0 += bf2f(u.x); a1 += bf2f(u.y); a2 += bf2f(u.z); a3 += bf2f(u.w);    \
    }

// Fused layer-1 pull + layer-2 MFMA GEMM. Block = 4 waves x 16 nodes.
// Gather: 4 passes of 4 nodes (16 lanes/node), h = di*raw + b1 -> LDS [16][68].
// MFMA: A-frags from LDS, B from W2Tb, g2b = bf16(acc*di).
__launch_bounds__(TPB)
__global__ void k_fused1(const int* __restrict__ ell, const unsigned short* __restrict__ g1b,
                         const float* __restrict__ dinv, const float* __restrict__ b1,
                         const unsigned short* __restrict__ W2Tb, const int* __restrict__ cnt,
                         const float* __restrict__ ovfacc, unsigned short* __restrict__ g2b,
                         int n_nodes) {
    __shared__ float Hs[4][16][68];  // padded: bank-safe, 16B-aligned rows
    int t = threadIdx.x;
    int w = t >> 6, lane = t & 63;
    int g4 = lane >> 4, fl = lane & 15;
    int n0 = (blockIdx.x * 4 + w) * 16;

#pragma unroll
    for (int p = 0; p < 4; ++p) {
        int node = n0 + p * 4 + g4;
        int an = node < n_nodes ? node : (n_nodes - 1);
        const int4* ep = (const int4*)(ell + (size_t)an * W_ELL);
        int4 i0 = ep[0], i1 = ep[1], i2 = ep[2], i3 = ep[3], i4 = ep[4];
        ushort4 su = ((const ushort4*)(g1b + (size_t)an * 64))[fl];
        float a0 = bf2f(su.x), a1 = bf2f(su.y), a2 = bf2f(su.z), a3 = bf2f(su.w);
        GATH64(i0.x) GATH64(i0.y) GATH64(i0.z) GATH64(i0.w)
        GATH64(i1.x) GATH64(i1.y) GATH64(i1.z) GATH64(i1.w)
        GATH64(i2.x) GATH64(i2.y) GATH64(i2.z) GATH64(i2.w)
        GATH64(i3.x) GATH64(i3.y) GATH64(i3.z) GATH64(i3.w)
        GATH64(i4.x) GATH64(i4.y) GATH64(i4.z) GATH64(i4.w)
        if (cnt[an] > W_ELL) {  // rare (~1%): add pre-accumulated overflow row
            float4 ov = ((const float4*)(ovfacc + (size_t)an * 64))[fl];
            a0 += ov.x; a1 += ov.y; a2 += ov.z; a3 += ov.w;
        }
        float di = dinv[an];
        float4 bb = ((const float4*)b1)[fl];
        float4 h;
        h.x = di * a0 + bb.x;
        h.y = di * a1 + bb.y;
        h.z = di * a2 + bb.z;
        h.w = di * a3 + bb.w;
        *(float4*)&Hs[w][p * 4 + g4][fl * 4] = h;
    }
    __syncthreads();

    if (n0 >= n_nodes) return;
    int r = lane & 15, kb = lane >> 4;
    const float* hp = &Hs[w][r][0];
    float4 v0 = *(const float4*)(hp + kb * 8);
    float4 v1 = *(const float4*)(hp + kb * 8 + 4);
    float4 v2 = *(const float4*)(hp + 32 + kb * 8);
    float4 v3 = *(const float4*)(hp + 32 + kb * 8 + 4);
    union { bf16x8 v; unsigned short e[8]; } a0u, a1u;
    a0u.e[0] = f2bf(v0.x); a0u.e[1] = f2bf(v0.y); a0u.e[2] = f2bf(v0.z); a0u.e[3] = f2bf(v0.w);
    a0u.e[4] = f2bf(v1.x); a0u.e[5] = f2bf(v1.y); a0u.e[6] = f2bf(v1.z); a0u.e[7] = f2bf(v1.w);
    a1u.e[0] = f2bf(v2.x); a1u.e[1] = f2bf(v2.y); a1u.e[2] = f2bf(v2.z); a1u.e[3] = f2bf(v2.w);
    a1u.e[4] = f2bf(v3.x); a1u.e[5] = f2bf(v3.y); a1u.e[6] = f2bf(v3.z); a1u.e[7] = f2bf(v3.w);

    int rnode = n0 + 4 * kb;
    float d[4];
    bool full = (n0 + 16 <= n_nodes);
    if (full) {
        float4 d4 = *(const float4*)(dinv + rnode);
        d[0] = d4.x; d[1] = d4.y; d[2] = d4.z; d[3] = d4.w;
    } else {
#pragma unroll
        for (int j = 0; j < 4; ++j) {
            int n2 = rnode + j;
            d[j] = (n2 < n_nodes) ? dinv[n2] : 0.f;
        }
    }

#pragma unroll
    for (int ft = 0; ft < 2; ++ft) {
        const unsigned short* wp = W2Tb + (size_t)(ft * 16 + r) * 64 + kb * 8;
        bf16x8 b0 = *(const bf16x8*)wp;
        bf16x8 b1v = *(const bf16x8*)(wp + 32);
        f32x4 acc = {0.f, 0.f, 0.f, 0.f};
        acc = __builtin_amdgcn_mfma_f32_16x16x32_bf16(a0u.v, b0, acc, 0, 0, 0);
        acc = __builtin_amdgcn_mfma_f32_16x16x32_bf16(a1u.v, b1v, acc, 0, 0, 0);
#pragma unroll
        for (int j = 0; j < 4; ++j) {
            int n2 = rnode + j;
            if (n2 < n_nodes) g2b[(size_t)n2 * 32 + ft * 16 + r] = f2bf(acc[j] * d[j]);
        }
    }
}

#define GATH32(S)                                                              \
    {                                                                          \
        ushort4 u = ((const ushort4*)(g2b + (size_t)(S) * 32))[fl];            \
        a0 += bf2f(u.x); a1 += bf2f(u.y); a2 += bf2f(u.z); a3 += bf2f(u.w);    \
    }

// Layer-2 ELL pull, final affine fused: out = di*(self+sum) + b2.
__launch_bounds__(TPB)
__global__ void k_ell2(const int* __restrict__ ell, const unsigned short* __restrict__ g2b,
                       const float* __restrict__ dinv, const float* __restrict__ b2,
                       float* __restrict__ out, int n_nodes) {
    int t = threadIdx.x;
    int lane = t & 63;
    int g = lane >> 3, fl = lane & 7;
    int node = blockIdx.x * 32 + (t >> 6) * 8 + g;
    if (node >= n_nodes) return;
    const int4* ep = (const int4*)(ell + (size_t)node * W_ELL);
    int4 i0 = ep[0], i1 = ep[1], i2 = ep[2], i3 = ep[3], i4 = ep[4];
    ushort4 su = ((const ushort4*)(g2b + (size_t)node * 32))[fl];
    float a0 = bf2f(su.x), a1 = bf2f(su.y), a2 = bf2f(su.z), a3 = bf2f(su.w);
    GATH32(i0.x) GATH32(i0.y) GATH32(i0.z) GATH32(i0.w)
    GATH32(i1.x) GATH32(i1.y) GATH32(i1.z) GATH32(i1.w)
    GATH32(i2.x) GATH32(i2.y) GATH32(i2.z) GATH32(i2.w)
    GATH32(i3.x) GATH32(i3.y) GATH32(i3.z) GATH32(i3.w)
    GATH32(i4.x) GATH32(i4.y) GATH32(i4.z) GATH32(i4.w)
    float di = dinv[node];
    float4 bb = ((const float4*)b2)[fl];
    float4 o;
    o.x = di * a0 + bb.x;
    o.y = di * a1 + bb.y;
    o.z = di * a2 + bb.z;
    o.w = di * a3 + bb.w;
    ((float4*)(out + (size_t)node * 32))[fl] = o;
}

// Overflow layer 2: scaled fp32 atomics into final out (+= di_dst * val).
__global__ void k_oflow2(const int* __restrict__ ovf, const int* __restrict__ ovf_cnt,
                         const unsigned short* __restrict__ g2b, const float* __restrict__ dinv,
                         float* __restrict__ out) {
    int n = *ovf_cnt;
    int total = n * 8;
    for (int i = blockIdx.x * blockDim.x + threadIdx.x; i < total;
         i += gridDim.x * blockDim.x) {
        int e = i >> 3, fl = i & 7;
        int src = ovf[2 * e], dst = ovf[2 * e + 1];
        float di = dinv[dst];
        ushort4 u = ((const ushort4*)(g2b + (size_t)src * 32))[fl];
        float* op = out + (size_t)dst * 32 + fl * 4;
        atomicAdd(op + 0, di * bf2f(u.x));
        atomicAdd(op + 1, di * bf2f(u.y));
        atomicAdd(op + 2, di * bf2f(u.z));
        atomicAdd(op + 3, di * bf2f(u.w));
    }
}

extern "C" void kernel_launch(void* const* d_in, const int* in_sizes, int n_in,
                              void* d_out, int out_size, void* d_ws, size_t ws_size,
                              hipStream_t stream) {
    const float* x  = (const float*)d_in[0];
    const void*  ei = d_in[1];
    const float* W1 = (const float*)d_in[2];
    const float* b1 = (const float*)d_in[3];
    const float* W2 = (const float*)d_in[4];
    const float* b2 = (const float*)d_in[5];
    float* out = (float*)d_out;

    const int n_nodes = in_sizes[0] / 64;
    const int E = in_sizes[1] / 2;
    const int nb = (n_nodes + NPB - 1) / NPB;  // 196 (<= 256)

    char* p = (char*)d_ws;
    auto carve = [&](size_t bytes) {
        char* r = p;
        p += (bytes + 255) / 256 * 256;
        return r;
    };
    int* flag      = (int*)carve(sizeof(int));
    int* bucket_wp = (int*)carve(256 * sizeof(int));
    int* ovf_cnt   = (int*)carve(sizeof(int));
    int* cnt       = (int*)carve((size_t)n_nodes * sizeof(int));
    float* dinv    = (float*)carve((size_t)n_nodes * sizeof(float));
    unsigned int* gstage = (unsigned int*)carve((size_t)nb * BCAP * sizeof(unsigned int));
    int* ell       = (int*)carve((size_t)nb * NPB * W_ELL * sizeof(int));
    int* ovf       = (int*)carve((size_t)E * 2 * sizeof(int));
    unsigned short* g1b = (unsigned short*)carve(((size_t)n_nodes + 1) * 64 * sizeof(unsigned short));
    unsigned short* g2b = (unsigned short*)carve(((size_t)n_nodes + 1) * 32 * sizeof(unsigned short));
    float* ovfacc  = (float*)carve((size_t)n_nodes * 64 * sizeof(float));
    unsigned short* W1Tb = (unsigned short*)carve(64 * 64 * sizeof(unsigned short));
    unsigned short* W2Tb = (unsigned short*)carve(32 * 64 * sizeof(unsigned short));

    k_detect<<<1, TPB, 0, stream>>>((const unsigned int*)ei, in_sizes[1], flag, bucket_wp,
                                    ovf_cnt, g1b, g2b, n_nodes, W1, W2, W1Tb, W2Tb);
    k_binA<<<(E + TILE_E - 1) / TILE_E, TPB, 0, stream>>>(ei, flag, E, nb, gstage, bucket_wp);
    k_ellB<<<nb, 512, 0, stream>>>(gstage, bucket_wp, ell, cnt, ovf, ovf_cnt, ovfacc, n_nodes);
    k_gemm1<<<(n_nodes + 63) / 64, TPB, 0, stream>>>(x, W1Tb, cnt, dinv, g1b, n_nodes);
    k_oflow1<<<64, TPB, 0, stream>>>(ovf, ovf_cnt, g1b, ovfacc);
    k_fused1<<<(n_nodes + 63) / 64, TPB, 0, stream>>>(ell, g1b, dinv, b1, W2Tb, cnt, ovfacc,
                                                      g2b, n_nodes);
    k_ell2<<<(n_nodes + 31) / 32, TPB, 0, stream>>>(ell, g2b, dinv, b2, out, n_nodes);
    k_oflow2<<<64, TPB, 0, stream>>>(ovf, ovf_cnt, g2b, dinv, out);
}

// Round 11
// 122.211 us; speedup vs baseline: 7.1628x; 1.0983x over previous
//
#include <hip/hip_runtime.h>

// 2-layer GCN: ELL pull + MFMA GEMMs, fused layer1-pull+layer2-GEMM.
// detect(2blk: flag/zero | W^T bf16) -> binA(4096-edge tiles) -> ellB (+ovfacc zero)
//  -> gemm1(MFMA) -> oflow1 -> fused1 (gather[skip-tail] + di*raw+b1 -> LDS -> MFMA)
//  -> ell2 (gather[skip-tail] + di*sum+b2 -> out) -> oflow2 (scaled atomics)

#define TPB 256
#define NPB 512     // nodes per bucket (dst >> 9)
#define BCAP 8192   // max edges per bucket (mean ~6122)
#define TILE_E 4096 // edges per binning block (512 threads x 8)
#define W_ELL 20    // ELL width (Poisson(12): ~1.6% rows overflow)

typedef __attribute__((ext_vector_type(8))) short bf16x8;
typedef __attribute__((ext_vector_type(4))) float f32x4;

__device__ __forceinline__ float bf2f(unsigned short u) {
    unsigned int v = ((unsigned int)u) << 16;
    return __builtin_bit_cast(float, v);
}
__device__ __forceinline__ unsigned short f2bf(float f) {
    unsigned int u = __builtin_bit_cast(unsigned int, f);
    u += 0x7FFFu + ((u >> 16) & 1u);  // RNE
    return (unsigned short)(u >> 16);
}
__device__ __forceinline__ int edge_val(const void* ei, int is64, long long idx) {
    if (is64) return (int)((const long long*)ei)[idx];
    return ((const int*)ei)[idx];
}

// Block 0: int64-detect + zero bucket_wp/ovf_cnt/zero-rows. Block 1: bf16 W^T tables.
__global__ void k_detect(const unsigned int* __restrict__ w, int nelems, int* flag,
                         int* __restrict__ bucket_wp, int* __restrict__ ovf_cnt,
                         unsigned short* __restrict__ g1b, unsigned short* __restrict__ g2b,
                         int n_nodes, const float* __restrict__ W1, const float* __restrict__ W2,
                         unsigned short* __restrict__ W1Tb, unsigned short* __restrict__ W2Tb) {
    int t = threadIdx.x;
    if (blockIdx.x == 1) {
        __shared__ float tr[64][65];
        // W1 (64x64 [k][f]) -> W1Tb (64x64 [f][k] bf16)
        for (int i = t; i < 4096; i += TPB) tr[i >> 6][i & 63] = W1[i];
        __syncthreads();
        for (int i = t; i < 4096; i += TPB) {
            int f = i >> 6, k = i & 63;
            W1Tb[i] = f2bf(tr[k][f]);
        }
        __syncthreads();
        // W2 (64x32 [k][f]) -> W2Tb (32x64 [f][k] bf16)
        for (int i = t; i < 2048; i += TPB) tr[i >> 5][i & 31] = W2[i];
        __syncthreads();
        for (int i = t; i < 2048; i += TPB) {
            int f = i >> 6, k = i & 63;
            W2Tb[i] = f2bf(tr[k][f]);
        }
        return;
    }
    __shared__ unsigned int red[TPB];
    bucket_wp[t] = 0;
    if (t == 0) *ovf_cnt = 0;
    if (t < 64) g1b[(size_t)n_nodes * 64 + t] = 0;
    if (t < 32) g2b[(size_t)n_nodes * 32 + t] = 0;
    unsigned int acc = 0;
    int limit = nelems < 16384 ? nelems : 16384;
    for (int i = 1 + 2 * t; i < limit; i += 2 * TPB) acc |= w[i];
    red[t] = acc;
    __syncthreads();
    for (int s = TPB / 2; s > 0; s >>= 1) {
        if (t < s) red[t] |= red[t + s];
        __syncthreads();
    }
    if (t == 0) *flag = (red[0] == 0u) ? 1 : 0;
}

// Pass A: bin edges by bucket = dst>>9 into gstage (bucket-major, BCAP stride).
// 512 threads x 8 edges. LDS-staged for chunked global writes.
__launch_bounds__(512)
__global__ void k_binA(const void* __restrict__ ei, const int* __restrict__ flag, int E,
                       int nb, unsigned int* __restrict__ gstage, int* __restrict__ bucket_wp) {
    __shared__ int lcnt[256];
    __shared__ int lboff[256];
    __shared__ int lrank[256];
    __shared__ int gbase[256];
    __shared__ int sh[256];
    __shared__ unsigned int spair[TILE_E];
    __shared__ unsigned char sbuck[TILE_E];
    int is64 = *flag;
    int t = threadIdx.x;
    int base_e = blockIdx.x * TILE_E;
    int ne = E - base_e;
    if (ne > TILE_E) ne = TILE_E;

    if (t < 256) {
        lcnt[t] = 0;
        lrank[t] = 0;
    }
    __syncthreads();

    int myb[8];
    unsigned int mypair[8];
#pragma unroll
    for (int k = 0; k < 8; ++k) {
        int idx = t + k * 512;
        myb[k] = -1;
        if (idx < ne) {
            long long e = base_e + idx;
            int s = edge_val(ei, is64, e);
            int d = edge_val(ei, is64, (long long)E + e);
            int b = d >> 9;
            myb[k] = b;
            mypair[k] = (unsigned int)s | ((unsigned int)(d & (NPB - 1)) << 20);
            atomicAdd(&lcnt[b], 1);
        }
    }
    __syncthreads();

    int v0 = (t < 256) ? lcnt[t] : 0;
    if (t < 256) sh[t] = v0;
    __syncthreads();
    for (int st = 1; st < 256; st <<= 1) {
        int u = (t >= st && t < 256) ? sh[t - st] : 0;
        __syncthreads();
        if (t < 256) sh[t] += u;
        __syncthreads();
    }
    if (t < 256) {
        lboff[t] = sh[t] - v0;
        if (t < nb && v0 > 0) gbase[t] = atomicAdd(&bucket_wp[t], v0);
    }
    __syncthreads();

#pragma unroll
    for (int k = 0; k < 8; ++k) {
        int b = myb[k];
        if (b >= 0) {
            int r = atomicAdd(&lrank[b], 1);
            int slot = lboff[b] + r;
            spair[slot] = mypair[k];
            sbuck[slot] = (unsigned char)b;
        }
    }
    __syncthreads();

    for (int j = t; j < ne; j += 512) {
        int b = sbuck[j];
        int pos = gbase[b] + (j - lboff[b]);
        if (pos < BCAP) gstage[(size_t)b * BCAP + pos] = spair[j];
    }
}

// Per bucket: build ELL slab (512 x 20) in LDS, overflow to list + zero ovfacc rows.
__launch_bounds__(512)
__global__ void k_ellB(const unsigned int* __restrict__ gstage, const int* __restrict__ bucket_wp,
                       int* __restrict__ ell, int* __restrict__ cnt, int* __restrict__ ovf,
                       int* __restrict__ ovf_cnt, float* __restrict__ ovfacc, int n_nodes) {
    __shared__ int lrank[NPB];
    __shared__ int slab[NPB * W_ELL];  // 40 KB
    int b = blockIdx.x, t = threadIdx.x;
    int zr = n_nodes;
    lrank[t] = 0;
    {
        int4 z4 = make_int4(zr, zr, zr, zr);
        for (int j = t; j < NPB * W_ELL / 4; j += 512) ((int4*)slab)[j] = z4;
    }
    __syncthreads();
    int cb = bucket_wp[b];
    if (cb > BCAP) cb = BCAP;
    const unsigned int* gp = gstage + (size_t)b * BCAP;
    for (int j = t; j < cb; j += 512) {
        unsigned int w = gp[j];
        int dl = (int)(w >> 20);
        int src = (int)(w & 0xFFFFFu);
        int r = atomicAdd(&lrank[dl], 1);
        if (r < W_ELL) {
            slab[dl * W_ELL + r] = src;
        } else {
            int o = atomicAdd(ovf_cnt, 1);
            ovf[2 * o] = src;
            ovf[2 * o + 1] = b * NPB + dl;
        }
    }
    __syncthreads();
    int node = b * NPB + t;
    if (node < n_nodes) {
        cnt[node] = lrank[t];
        if (lrank[t] > W_ELL) {  // zero this node's overflow accumulator row
            float4 z = make_float4(0.f, 0.f, 0.f, 0.f);
            float4* zp = (float4*)(ovfacc + (size_t)node * 64);
#pragma unroll
            for (int j = 0; j < 16; ++j) zp[j] = z;
        }
    }
    {
        int4* dst = (int4*)(ell + (size_t)b * (NPB * W_ELL));
        for (int j = t; j < NPB * W_ELL / 4; j += 512) dst[j] = ((int4*)slab)[j];
    }
}

// MFMA gemm1: g1b = bf16((x@W1)*dinv). Wave = 16-node tile; 4 feature-tiles.
__launch_bounds__(TPB)
__global__ void k_gemm1(const float* __restrict__ x, const unsigned short* __restrict__ W1Tb,
                        const int* __restrict__ cnt, float* __restrict__ dinv,
                        unsigned short* __restrict__ g1b, int n_nodes) {
    int t = threadIdx.x;
    int w = t >> 6, lane = t & 63;
    int r = lane & 15, kb = lane >> 4;
    int nb = (blockIdx.x * 4 + w) * 16;
    if (nb >= n_nodes) return;
    int ar = nb + r;
    if (ar > n_nodes - 1) ar = n_nodes - 1;
    const float* xp = x + (size_t)ar * 64 + kb * 8;
    float4 v0 = ((const float4*)xp)[0];
    float4 v1 = ((const float4*)xp)[1];
    float4 v2 = ((const float4*)(xp + 32))[0];
    float4 v3 = ((const float4*)(xp + 32))[1];
    union { bf16x8 v; unsigned short e[8]; } a0, a1;
    a0.e[0] = f2bf(v0.x); a0.e[1] = f2bf(v0.y); a0.e[2] = f2bf(v0.z); a0.e[3] = f2bf(v0.w);
    a0.e[4] = f2bf(v1.x); a0.e[5] = f2bf(v1.y); a0.e[6] = f2bf(v1.z); a0.e[7] = f2bf(v1.w);
    a1.e[0] = f2bf(v2.x); a1.e[1] = f2bf(v2.y); a1.e[2] = f2bf(v2.z); a1.e[3] = f2bf(v2.w);
    a1.e[4] = f2bf(v3.x); a1.e[5] = f2bf(v3.y); a1.e[6] = f2bf(v3.z); a1.e[7] = f2bf(v3.w);

    int rnode = nb + 4 * kb;
    float d[4];
    bool full = (nb + 16 <= n_nodes);
    if (full) {
        int4 c4 = *(const int4*)(cnt + rnode);
        d[0] = rsqrtf((float)(c4.x + 1));
        d[1] = rsqrtf((float)(c4.y + 1));
        d[2] = rsqrtf((float)(c4.z + 1));
        d[3] = rsqrtf((float)(c4.w + 1));
        if (r == 0) *(float4*)(dinv + rnode) = make_float4(d[0], d[1], d[2], d[3]);
    } else {
#pragma unroll
        for (int j = 0; j < 4; ++j) {
            int n2 = rnode + j;
            d[j] = (n2 < n_nodes) ? rsqrtf((float)(cnt[n2] + 1)) : 0.f;
            if (r == 0 && n2 < n_nodes) dinv[n2] = d[j];
        }
    }

#pragma unroll
    for (int ft = 0; ft < 4; ++ft) {
        const unsigned short* bp = W1Tb + (size_t)(ft * 16 + r) * 64 + kb * 8;
        bf16x8 b0 = *(const bf16x8*)bp;
        bf16x8 b1v = *(const bf16x8*)(bp + 32);
        f32x4 acc = {0.f, 0.f, 0.f, 0.f};
        acc = __builtin_amdgcn_mfma_f32_16x16x32_bf16(a0.v, b0, acc, 0, 0, 0);
        acc = __builtin_amdgcn_mfma_f32_16x16x32_bf16(a1.v, b1v, acc, 0, 0, 0);
#pragma unroll
        for (int j = 0; j < 4; ++j) {
            int n2 = rnode + j;
            if (n2 < n_nodes) g1b[(size_t)n2 * 64 + ft * 16 + r] = f2bf(acc[j] * d[j]);
        }
    }
}

// Overflow layer 1: raw fp32 atomics into ovfacc (rows pre-zeroed by ellB).
__global__ void k_oflow1(const int* __restrict__ ovf, const int* __restrict__ ovf_cnt,
                         const unsigned short* __restrict__ g1b, float* __restrict__ ovfacc) {
    int n = *ovf_cnt;
    int total = n * 16;
    for (int i = blockIdx.x * blockDim.x + threadIdx.x; i < total;
         i += gridDim.x * blockDim.x) {
        int e = i >> 4, fl = i & 15;
        int src = ovf[2 * e], dst = ovf[2 * e + 1];
        ushort4 u = ((const ushort4*)(g1b + (size_t)src * 64))[fl];
        float* hp = ovfacc + (size_t)dst * 64 + fl * 4;
        atomicAdd(hp + 0, bf2f(u.x));
        atomicAdd(hp + 1, bf2f(u.y));
        atomicAdd(hp + 2, bf2f(u.z));
        atomicAdd(hp + 3, bf2f(u.w));
    }
}

#define GATH64(S)                                                              \
    {                                                                          \
        ushort4 u = ((const ushort4*)(g1b + (size_t)(S) * 64))[fl];            \
        a0 += bf2f(u.x); a1 += bf2f(u.y); a2 += bf2f(u.z); a3 += bf2f(u.w);    \
    }

// Fused layer-1 pull + layer-2 MFMA GEMM. Block = 4 waves x 16 nodes.
// Slots 16..19 skipped when the whole wave's nodes have cnt<=16 (exact: pads are zero-row).
__launch_bounds__(TPB)
__global__ void k_fused1(const int* __restrict__ ell, const unsigned short* __restrict__ g1b,
                         const float* __restrict__ dinv, const float* __restrict__ b1,
                         const unsigned short* __restrict__ W2Tb, const int* __restrict__ cnt,
                         const float* __restrict__ ovfacc, unsigned short* __restrict__ g2b,
                         int n_nodes) {
    __shared__ float Hs[4][16][68];  // padded rows, 16B-aligned
    int t = threadIdx.x;
    int w = t >> 6, lane = t & 63;
    int g4 = lane >> 4, fl = lane & 15;
    int n0 = (blockIdx.x * 4 + w) * 16;

#pragma unroll
    for (int p = 0; p < 4; ++p) {
        int node = n0 + p * 4 + g4;
        int an = node < n_nodes ? node : (n_nodes - 1);
        int cv = cnt[an];
        const int4* ep = (const int4*)(ell + (size_t)an * W_ELL);
        int4 i0 = ep[0], i1 = ep[1], i2 = ep[2], i3 = ep[3];
        ushort4 su = ((const ushort4*)(g1b + (size_t)an * 64))[fl];
        float a0 = bf2f(su.x), a1 = bf2f(su.y), a2 = bf2f(su.z), a3 = bf2f(su.w);
        GATH64(i0.x) GATH64(i0.y) GATH64(i0.z) GATH64(i0.w)
        GATH64(i1.x) GATH64(i1.y) GATH64(i1.z) GATH64(i1.w)
        GATH64(i2.x) GATH64(i2.y) GATH64(i2.z) GATH64(i2.w)
        GATH64(i3.x) GATH64(i3.y) GATH64(i3.z) GATH64(i3.w)
        if (__any(cv > 16)) {
            int4 i4 = ep[4];
            GATH64(i4.x) GATH64(i4.y) GATH64(i4.z) GATH64(i4.w)
        }
        if (cv > W_ELL) {  // rare (~1.6%): add pre-accumulated overflow row
            float4 ov = ((const float4*)(ovfacc + (size_t)an * 64))[fl];
            a0 += ov.x; a1 += ov.y; a2 += ov.z; a3 += ov.w;
        }
        float di = dinv[an];
        float4 bb = ((const float4*)b1)[fl];
        float4 h;
        h.x = di * a0 + bb.x;
        h.y = di * a1 + bb.y;
        h.z = di * a2 + bb.z;
        h.w = di * a3 + bb.w;
        *(float4*)&Hs[w][p * 4 + g4][fl * 4] = h;
    }
    __syncthreads();

    if (n0 >= n_nodes) return;
    int r = lane & 15, kb = lane >> 4;
    const float* hp = &Hs[w][r][0];
    float4 v0 = *(const float4*)(hp + kb * 8);
    float4 v1 = *(const float4*)(hp + kb * 8 + 4);
    float4 v2 = *(const float4*)(hp + 32 + kb * 8);
    float4 v3 = *(const float4*)(hp + 32 + kb * 8 + 4);
    union { bf16x8 v; unsigned short e[8]; } a0u, a1u;
    a0u.e[0] = f2bf(v0.x); a0u.e[1] = f2bf(v0.y); a0u.e[2] = f2bf(v0.z); a0u.e[3] = f2bf(v0.w);
    a0u.e[4] = f2bf(v1.x); a0u.e[5] = f2bf(v1.y); a0u.e[6] = f2bf(v1.z); a0u.e[7] = f2bf(v1.w);
    a1u.e[0] = f2bf(v2.x); a1u.e[1] = f2bf(v2.y); a1u.e[2] = f2bf(v2.z); a1u.e[3] = f2bf(v2.w);
    a1u.e[4] = f2bf(v3.x); a1u.e[5] = f2bf(v3.y); a1u.e[6] = f2bf(v3.z); a1u.e[7] = f2bf(v3.w);

    int rnode = n0 + 4 * kb;
    float d[4];
    bool full = (n0 + 16 <= n_nodes);
    if (full) {
        float4 d4 = *(const float4*)(dinv + rnode);
        d[0] = d4.x; d[1] = d4.y; d[2] = d4.z; d[3] = d4.w;
    } else {
#pragma unroll
        for (int j = 0; j < 4; ++j) {
            int n2 = rnode + j;
            d[j] = (n2 < n_nodes) ? dinv[n2] : 0.f;
        }
    }

#pragma unroll
    for (int ft = 0; ft < 2; ++ft) {
        const unsigned short* wp = W2Tb + (size_t)(ft * 16 + r) * 64 + kb * 8;
        bf16x8 b0 = *(const bf16x8*)wp;
        bf16x8 b1v = *(const bf16x8*)(wp + 32);
        f32x4 acc = {0.f, 0.f, 0.f, 0.f};
        acc = __builtin_amdgcn_mfma_f32_16x16x32_bf16(a0u.v, b0, acc, 0, 0, 0);
        acc = __builtin_amdgcn_mfma_f32_16x16x32_bf16(a1u.v, b1v, acc, 0, 0, 0);
#pragma unroll
        for (int j = 0; j < 4; ++j) {
            int n2 = rnode + j;
            if (n2 < n_nodes) g2b[(size_t)n2 * 32 + ft * 16 + r] = f2bf(acc[j] * d[j]);
        }
    }
}

#define GATH32(S)                                                              \
    {                                                                          \
        ushort4 u = ((const ushort4*)(g2b + (size_t)(S) * 32))[fl];            \
        a0 += bf2f(u.x); a1 += bf2f(u.y); a2 += bf2f(u.z); a3 += bf2f(u.w);    \
    }

// Layer-2 ELL pull, final affine fused: out = di*(self+sum) + b2.
__launch_bounds__(TPB)
__global__ void k_ell2(const int* __restrict__ ell, const unsigned short* __restrict__ g2b,
                       const float* __restrict__ dinv, const float* __restrict__ b2,
                       const int* __restrict__ cnt, float* __restrict__ out, int n_nodes) {
    int t = threadIdx.x;
    int lane = t & 63;
    int g = lane >> 3, fl = lane & 7;
    int node = blockIdx.x * 32 + (t >> 6) * 8 + g;
    if (node >= n_nodes) return;
    int cv = cnt[node];
    const int4* ep = (const int4*)(ell + (size_t)node * W_ELL);
    int4 i0 = ep[0], i1 = ep[1], i2 = ep[2], i3 = ep[3];
    ushort4 su = ((const ushort4*)(g2b + (size_t)node * 32))[fl];
    float a0 = bf2f(su.x), a1 = bf2f(su.y), a2 = bf2f(su.z), a3 = bf2f(su.w);
    GATH32(i0.x) GATH32(i0.y) GATH32(i0.z) GATH32(i0.w)
    GATH32(i1.x) GATH32(i1.y) GATH32(i1.z) GATH32(i1.w)
    GATH32(i2.x) GATH32(i2.y) GATH32(i2.z) GATH32(i2.w)
    GATH32(i3.x) GATH32(i3.y) GATH32(i3.z) GATH32(i3.w)
    if (__any(cv > 16)) {
        int4 i4 = ep[4];
        GATH32(i4.x) GATH32(i4.y) GATH32(i4.z) GATH32(i4.w)
    }
    float di = dinv[node];
    float4 bb = ((const float4*)b2)[fl];
    float4 o;
    o.x = di * a0 + bb.x;
    o.y = di * a1 + bb.y;
    o.z = di * a2 + bb.z;
    o.w = di * a3 + bb.w;
    ((float4*)(out + (size_t)node * 32))[fl] = o;
}

// Overflow layer 2: scaled fp32 atomics into final out (+= di_dst * val).
__global__ void k_oflow2(const int* __restrict__ ovf, const int* __restrict__ ovf_cnt,
                         const unsigned short* __restrict__ g2b, const float* __restrict__ dinv,
                         float* __restrict__ out) {
    int n = *ovf_cnt;
    int total = n * 8;
    for (int i = blockIdx.x * blockDim.x + threadIdx.x; i < total;
         i += gridDim.x * blockDim.x) {
        int e = i >> 3, fl = i & 7;
        int src = ovf[2 * e], dst = ovf[2 * e + 1];
        float di = dinv[dst];
        ushort4 u = ((const ushort4*)(g2b + (size_t)src * 32))[fl];
        float* op = out + (size_t)dst * 32 + fl * 4;
        atomicAdd(op + 0, di * bf2f(u.x));
        atomicAdd(op + 1, di * bf2f(u.y));
        atomicAdd(op + 2, di * bf2f(u.z));
        atomicAdd(op + 3, di * bf2f(u.w));
    }
}

extern "C" void kernel_launch(void* const* d_in, const int* in_sizes, int n_in,
                              void* d_out, int out_size, void* d_ws, size_t ws_size,
                              hipStream_t stream) {
    const float* x  = (const float*)d_in[0];
    const void*  ei = d_in[1];
    const float* W1 = (const float*)d_in[2];
    const float* b1 = (const float*)d_in[3];
    const float* W2 = (const float*)d_in[4];
    const float* b2 = (const float*)d_in[5];
    float* out = (float*)d_out;

    const int n_nodes = in_sizes[0] / 64;
    const int E = in_sizes[1] / 2;
    const int nb = (n_nodes + NPB - 1) / NPB;  // 196 (<= 256)

    char* p = (char*)d_ws;
    auto carve = [&](size_t bytes) {
        char* r = p;
        p += (bytes + 255) / 256 * 256;
        return r;
    };
    int* flag      = (int*)carve(sizeof(int));
    int* bucket_wp = (int*)carve(256 * sizeof(int));
    int* ovf_cnt   = (int*)carve(sizeof(int));
    int* cnt       = (int*)carve((size_t)n_nodes * sizeof(int));
    float* dinv    = (float*)carve((size_t)n_nodes * sizeof(float));
    unsigned int* gstage = (unsigned int*)carve((size_t)nb * BCAP * sizeof(unsigned int));
    int* ell       = (int*)carve((size_t)nb * NPB * W_ELL * sizeof(int));
    int* ovf       = (int*)carve((size_t)E * 2 * sizeof(int));
    unsigned short* g1b = (unsigned short*)carve(((size_t)n_nodes + 1) * 64 * sizeof(unsigned short));
    unsigned short* g2b = (unsigned short*)carve(((size_t)n_nodes + 1) * 32 * sizeof(unsigned short));
    float* ovfacc  = (float*)carve((size_t)n_nodes * 64 * sizeof(float));
    unsigned short* W1Tb = (unsigned short*)carve(64 * 64 * sizeof(unsigned short));
    unsigned short* W2Tb = (unsigned short*)carve(32 * 64 * sizeof(unsigned short));

    k_detect<<<2, TPB, 0, stream>>>((const unsigned int*)ei, in_sizes[1], flag, bucket_wp,
                                    ovf_cnt, g1b, g2b, n_nodes, W1, W2, W1Tb, W2Tb);
    k_binA<<<(E + TILE_E - 1) / TILE_E, 512, 0, stream>>>(ei, flag, E, nb, gstage, bucket_wp);
    k_ellB<<<nb, 512, 0, stream>>>(gstage, bucket_wp, ell, cnt, ovf, ovf_cnt, ovfacc, n_nodes);
    k_gemm1<<<(n_nodes + 63) / 64, TPB, 0, stream>>>(x, W1Tb, cnt, dinv, g1b, n_nodes);
    k_oflow1<<<64, TPB, 0, stream>>>(ovf, ovf_cnt, g1b, ovfacc);
    k_fused1<<<(n_nodes + 63) / 64, TPB, 0, stream>>>(ell, g1b, dinv, b1, W2Tb, cnt, ovfacc,
                                                      g2b, n_nodes);
    k_ell2<<<(n_nodes + 31) / 32, TPB, 0, stream>>>(ell, g2b, dinv, b2, cnt, out, n_nodes);
    k_oflow2<<<64, TPB, 0, stream>>>(ovf, ovf_cnt, g2b, dinv, out);
}

// Round 12
// 119.178 us; speedup vs baseline: 7.3451x; 1.0255x over previous
//
#include <hip/hip_runtime.h>

// 2-layer GCN, algebraically refactored: out = S·S·(X·W12) + (S·1)·(b1ᵀW2) + 1·b2ᵀ
// where S = D^-1/2 (A+I) D^-1/2, W12 = W1@W2 (64x32). Both aggregations 32-wide.
// detect(2blk: flag/zero | W12+c1) -> binA -> ellB -> gemm0(MFMA, T0=bf16(dinv·X@W12))
//  -> k_s (sraw = sum dinv[src] + dinv) -> oflow1 (T0+sraw atomics)
//  -> agg1 (T1 = bf16(dinv^2·(sum T0 + self + ovf))) -> oflow2 (T1 atomics)
//  -> agg2 (out = dinv·(sum T1 + self + ovf + sraw·c1) + b2)

#define TPB 256
#define NPB 512     // nodes per bucket (dst >> 9)
#define BCAP 8192   // max edges per bucket (mean ~6122)
#define TILE_E 4096 // edges per binning block (512 threads x 8)
#define W_ELL 20    // ELL width (Poisson(12): ~1.6% rows overflow)

typedef __attribute__((ext_vector_type(8))) short bf16x8;
typedef __attribute__((ext_vector_type(4))) float f32x4;

__device__ __forceinline__ float bf2f(unsigned short u) {
    unsigned int v = ((unsigned int)u) << 16;
    return __builtin_bit_cast(float, v);
}
__device__ __forceinline__ unsigned short f2bf(float f) {
    unsigned int u = __builtin_bit_cast(unsigned int, f);
    u += 0x7FFFu + ((u >> 16) & 1u);  // RNE
    return (unsigned short)(u >> 16);
}
__device__ __forceinline__ int edge_val(const void* ei, int is64, long long idx) {
    if (is64) return (int)((const long long*)ei)[idx];
    return ((const int*)ei)[idx];
}

// Block 0: int64-detect + zero bucket_wp/ovf_cnt/zero-rows/dinv[n].
// Block 1: W12 = W1@W2 (fp32) -> W12Tb bf16 [f][k]; c1 = b1ᵀW2 (fp32).
__global__ void k_detect(const unsigned int* __restrict__ w, int nelems, int* flag,
                         int* __restrict__ bucket_wp, int* __restrict__ ovf_cnt,
                         unsigned short* __restrict__ T0b, unsigned short* __restrict__ T1b,
                         float* __restrict__ dinv, int n_nodes,
                         const float* __restrict__ W1, const float* __restrict__ W2,
                         const float* __restrict__ b1,
                         unsigned short* __restrict__ W12Tb, float* __restrict__ c1) {
    int t = threadIdx.x;
    if (blockIdx.x == 1) {
        __shared__ float W1s[64][64];
        __shared__ float W2s[64][32];
        for (int i = t; i < 4096; i += TPB) W1s[i >> 6][i & 63] = W1[i];
        for (int i = t; i < 2048; i += TPB) W2s[i >> 5][i & 31] = W2[i];
        __syncthreads();
        // W12Tb[f][k] = bf16( sum_j W1[k][j]*W2[j][f] )
        for (int i = t; i < 2048; i += TPB) {
            int f = i >> 6, k = i & 63;
            float acc = 0.f;
#pragma unroll
            for (int j = 0; j < 64; ++j) acc += W1s[k][j] * W2s[j][f];
            W12Tb[i] = f2bf(acc);
        }
        if (t < 32) {
            float acc = 0.f;
#pragma unroll
            for (int j = 0; j < 64; ++j) acc += b1[j] * W2s[j][t];
            c1[t] = acc;
        }
        return;
    }
    __shared__ unsigned int red[TPB];
    bucket_wp[t] = 0;
    if (t == 0) {
        *ovf_cnt = 0;
        dinv[n_nodes] = 0.f;  // zero-row dinv for k_s pad gathers
    }
    if (t < 32) {
        T0b[(size_t)n_nodes * 32 + t] = 0;  // zero-rows for pad gathers
        T1b[(size_t)n_nodes * 32 + t] = 0;
    }
    unsigned int acc = 0;
    int limit = nelems < 16384 ? nelems : 16384;
    for (int i = 1 + 2 * t; i < limit; i += 2 * TPB) acc |= w[i];
    red[t] = acc;
    __syncthreads();
    for (int s = TPB / 2; s > 0; s >>= 1) {
        if (t < s) red[t] |= red[t + s];
        __syncthreads();
    }
    if (t == 0) *flag = (red[0] == 0u) ? 1 : 0;
}

// Pass A: bin edges by bucket = dst>>9 into gstage (bucket-major, BCAP stride).
__launch_bounds__(512)
__global__ void k_binA(const void* __restrict__ ei, const int* __restrict__ flag, int E,
                       int nb, unsigned int* __restrict__ gstage, int* __restrict__ bucket_wp) {
    __shared__ int lcnt[256];
    __shared__ int lboff[256];
    __shared__ int lrank[256];
    __shared__ int gbase[256];
    __shared__ int sh[256];
    __shared__ unsigned int spair[TILE_E];
    __shared__ unsigned char sbuck[TILE_E];
    int is64 = *flag;
    int t = threadIdx.x;
    int base_e = blockIdx.x * TILE_E;
    int ne = E - base_e;
    if (ne > TILE_E) ne = TILE_E;

    if (t < 256) {
        lcnt[t] = 0;
        lrank[t] = 0;
    }
    __syncthreads();

    int myb[8];
    unsigned int mypair[8];
#pragma unroll
    for (int k = 0; k < 8; ++k) {
        int idx = t + k * 512;
        myb[k] = -1;
        if (idx < ne) {
            long long e = base_e + idx;
            int s = edge_val(ei, is64, e);
            int d = edge_val(ei, is64, (long long)E + e);
            int b = d >> 9;
            myb[k] = b;
            mypair[k] = (unsigned int)s | ((unsigned int)(d & (NPB - 1)) << 20);
            atomicAdd(&lcnt[b], 1);
        }
    }
    __syncthreads();

    int v0 = (t < 256) ? lcnt[t] : 0;
    if (t < 256) sh[t] = v0;
    __syncthreads();
    for (int st = 1; st < 256; st <<= 1) {
        int u = (t >= st && t < 256) ? sh[t - st] : 0;
        __syncthreads();
        if (t < 256) sh[t] += u;
        __syncthreads();
    }
    if (t < 256) {
        lboff[t] = sh[t] - v0;
        if (t < nb && v0 > 0) gbase[t] = atomicAdd(&bucket_wp[t], v0);
    }
    __syncthreads();

#pragma unroll
    for (int k = 0; k < 8; ++k) {
        int b = myb[k];
        if (b >= 0) {
            int r = atomicAdd(&lrank[b], 1);
            int slot = lboff[b] + r;
            spair[slot] = mypair[k];
            sbuck[slot] = (unsigned char)b;
        }
    }
    __syncthreads();

    for (int j = t; j < ne; j += 512) {
        int b = sbuck[j];
        int pos = gbase[b] + (j - lboff[b]);
        if (pos < BCAP) gstage[(size_t)b * BCAP + pos] = spair[j];
    }
}

// Per bucket: ELL slab (512 x 20) in LDS; overflow list; zero ovfacc1/2 rows.
__launch_bounds__(512)
__global__ void k_ellB(const unsigned int* __restrict__ gstage, const int* __restrict__ bucket_wp,
                       int* __restrict__ ell, int* __restrict__ cnt, int* __restrict__ ovf,
                       int* __restrict__ ovf_cnt, float* __restrict__ ovfacc1,
                       float* __restrict__ ovfacc2, int n_nodes) {
    __shared__ int lrank[NPB];
    __shared__ int slab[NPB * W_ELL];  // 40 KB
    int b = blockIdx.x, t = threadIdx.x;
    int zr = n_nodes;
    lrank[t] = 0;
    {
        int4 z4 = make_int4(zr, zr, zr, zr);
        for (int j = t; j < NPB * W_ELL / 4; j += 512) ((int4*)slab)[j] = z4;
    }
    __syncthreads();
    int cb = bucket_wp[b];
    if (cb > BCAP) cb = BCAP;
    const unsigned int* gp = gstage + (size_t)b * BCAP;
    for (int j = t; j < cb; j += 512) {
        unsigned int w = gp[j];
        int dl = (int)(w >> 20);
        int src = (int)(w & 0xFFFFFu);
        int r = atomicAdd(&lrank[dl], 1);
        if (r < W_ELL) {
            slab[dl * W_ELL + r] = src;
        } else {
            int o = atomicAdd(ovf_cnt, 1);
            ovf[2 * o] = src;
            ovf[2 * o + 1] = b * NPB + dl;
        }
    }
    __syncthreads();
    int node = b * NPB + t;
    if (node < n_nodes) {
        cnt[node] = lrank[t];
        if (lrank[t] > W_ELL) {  // zero both overflow accumulator rows
            float4 z = make_float4(0.f, 0.f, 0.f, 0.f);
            float4* z1 = (float4*)(ovfacc1 + (size_t)node * 32);
            float4* z2 = (float4*)(ovfacc2 + (size_t)node * 32);
#pragma unroll
            for (int j = 0; j < 8; ++j) {
                z1[j] = z;
                z2[j] = z;
            }
        }
    }
    {
        int4* dst = (int4*)(ell + (size_t)b * (NPB * W_ELL));
        for (int j = t; j < NPB * W_ELL / 4; j += 512) dst[j] = ((int4*)slab)[j];
    }
}

// MFMA gemm0: T0b = bf16((x@W12)*dinv), 32-wide. Wave = 16-node tile, 2 feature-tiles.
// A-frag: row=lane&15, k=8*(lane>>4)+j (+32 for 2nd MFMA). D: row=4*(lane>>4)+reg, col=lane&15.
__launch_bounds__(TPB)
__global__ void k_gemm0(const float* __restrict__ x, const unsigned short* __restrict__ W12Tb,
                        const int* __restrict__ cnt, float* __restrict__ dinv,
                        unsigned short* __restrict__ T0b, int n_nodes) {
    int t = threadIdx.x;
    int w = t >> 6, lane = t & 63;
    int r = lane & 15, kb = lane >> 4;
    int nb = (blockIdx.x * 4 + w) * 16;
    if (nb >= n_nodes) return;
    int ar = nb + r;
    if (ar > n_nodes - 1) ar = n_nodes - 1;
    const float* xp = x + (size_t)ar * 64 + kb * 8;
    float4 v0 = ((const float4*)xp)[0];
    float4 v1 = ((const float4*)xp)[1];
    float4 v2 = ((const float4*)(xp + 32))[0];
    float4 v3 = ((const float4*)(xp + 32))[1];
    union { bf16x8 v; unsigned short e[8]; } a0, a1;
    a0.e[0] = f2bf(v0.x); a0.e[1] = f2bf(v0.y); a0.e[2] = f2bf(v0.z); a0.e[3] = f2bf(v0.w);
    a0.e[4] = f2bf(v1.x); a0.e[5] = f2bf(v1.y); a0.e[6] = f2bf(v1.z); a0.e[7] = f2bf(v1.w);
    a1.e[0] = f2bf(v2.x); a1.e[1] = f2bf(v2.y); a1.e[2] = f2bf(v2.z); a1.e[3] = f2bf(v2.w);
    a1.e[4] = f2bf(v3.x); a1.e[5] = f2bf(v3.y); a1.e[6] = f2bf(v3.z); a1.e[7] = f2bf(v3.w);

    int rnode = nb + 4 * kb;
    float d[4];
    bool full = (nb + 16 <= n_nodes);
    if (full) {
        int4 c4 = *(const int4*)(cnt + rnode);
        d[0] = rsqrtf((float)(c4.x + 1));
        d[1] = rsqrtf((float)(c4.y + 1));
        d[2] = rsqrtf((float)(c4.z + 1));
        d[3] = rsqrtf((float)(c4.w + 1));
        if (r == 0) *(float4*)(dinv + rnode) = make_float4(d[0], d[1], d[2], d[3]);
    } else {
#pragma unroll
        for (int j = 0; j < 4; ++j) {
            int n2 = rnode + j;
            d[j] = (n2 < n_nodes) ? rsqrtf((float)(cnt[n2] + 1)) : 0.f;
            if (r == 0 && n2 < n_nodes) dinv[n2] = d[j];
        }
    }

#pragma unroll
    for (int ft = 0; ft < 2; ++ft) {
        const unsigned short* bp = W12Tb + (size_t)(ft * 16 + r) * 64 + kb * 8;
        bf16x8 b0 = *(const bf16x8*)bp;
        bf16x8 b1v = *(const bf16x8*)(bp + 32);
        f32x4 acc = {0.f, 0.f, 0.f, 0.f};
        acc = __builtin_amdgcn_mfma_f32_16x16x32_bf16(a0.v, b0, acc, 0, 0, 0);
        acc = __builtin_amdgcn_mfma_f32_16x16x32_bf16(a1.v, b1v, acc, 0, 0, 0);
#pragma unroll
        for (int j = 0; j < 4; ++j) {
            int n2 = rnode + j;
            if (n2 < n_nodes) T0b[(size_t)n2 * 32 + ft * 16 + r] = f2bf(acc[j] * d[j]);
        }
    }
}

// sraw[d] = sum_{ell} dinv[src] + dinv[d]. 4 lanes/node, 16 nodes/wave.
__launch_bounds__(TPB)
__global__ void k_s(const int* __restrict__ ell, const float* __restrict__ dinv,
                    float* __restrict__ sraw, int n_nodes) {
    int t = threadIdx.x;
    int w = t >> 6, lane = t & 63;
    int node = blockIdx.x * 64 + w * 16 + (lane >> 2);
    int j0 = lane & 3;
    if (node >= n_nodes) return;
    const int* ep = ell + (size_t)node * W_ELL;
    float a = dinv[ep[j0]] + dinv[ep[4 + j0]] + dinv[ep[8 + j0]] + dinv[ep[12 + j0]]
            + dinv[ep[16 + j0]];
    a += __shfl_xor(a, 1);
    a += __shfl_xor(a, 2);
    if (j0 == 0) sraw[node] = a + dinv[node];
}

// Overflow pass 1: T0 row atomics into ovfacc1; dinv[src] atomics into sraw.
__global__ void k_oflow1(const int* __restrict__ ovf, const int* __restrict__ ovf_cnt,
                         const unsigned short* __restrict__ T0b, const float* __restrict__ dinv,
                         float* __restrict__ ovfacc1, float* __restrict__ sraw) {
    int n = *ovf_cnt;
    int total = n * 8;
    for (int i = blockIdx.x * blockDim.x + threadIdx.x; i < total;
         i += gridDim.x * blockDim.x) {
        int e = i >> 3, fl = i & 7;
        int src = ovf[2 * e], dst = ovf[2 * e + 1];
        ushort4 u = ((const ushort4*)(T0b + (size_t)src * 32))[fl];
        float* hp = ovfacc1 + (size_t)dst * 32 + fl * 4;
        atomicAdd(hp + 0, bf2f(u.x));
        atomicAdd(hp + 1, bf2f(u.y));
        atomicAdd(hp + 2, bf2f(u.z));
        atomicAdd(hp + 3, bf2f(u.w));
        if (fl == 0) atomicAdd(&sraw[dst], dinv[src]);
    }
}

#define GATH32(TBL, S)                                                         \
    {                                                                          \
        ushort4 u = ((const ushort4*)(TBL + (size_t)(S) * 32))[fl];            \
        a0 += bf2f(u.x); a1 += bf2f(u.y); a2 += bf2f(u.z); a3 += bf2f(u.w);    \
    }

// Aggregation 1: T1b = bf16(dinv^2 * (sum T0[src] + T0[self] + ovf)). 8 lanes/node.
__launch_bounds__(TPB)
__global__ void k_agg1(const int* __restrict__ ell, const unsigned short* __restrict__ T0b,
                       const float* __restrict__ dinv, const int* __restrict__ cnt,
                       const float* __restrict__ ovfacc1, unsigned short* __restrict__ T1b,
                       int n_nodes) {
    int t = threadIdx.x;
    int lane = t & 63;
    int g = lane >> 3, fl = lane & 7;
    int node = blockIdx.x * 32 + (t >> 6) * 8 + g;
    if (node >= n_nodes) return;
    int cv = cnt[node];
    const int4* ep = (const int4*)(ell + (size_t)node * W_ELL);
    int4 i0 = ep[0], i1 = ep[1], i2 = ep[2], i3 = ep[3];
    ushort4 su = ((const ushort4*)(T0b + (size_t)node * 32))[fl];
    float a0 = bf2f(su.x), a1 = bf2f(su.y), a2 = bf2f(su.z), a3 = bf2f(su.w);
    GATH32(T0b, i0.x) GATH32(T0b, i0.y) GATH32(T0b, i0.z) GATH32(T0b, i0.w)
    GATH32(T0b, i1.x) GATH32(T0b, i1.y) GATH32(T0b, i1.z) GATH32(T0b, i1.w)
    GATH32(T0b, i2.x) GATH32(T0b, i2.y) GATH32(T0b, i2.z) GATH32(T0b, i2.w)
    GATH32(T0b, i3.x) GATH32(T0b, i3.y) GATH32(T0b, i3.z) GATH32(T0b, i3.w)
    if (__any(cv > 16)) {
        int4 i4 = ep[4];
        GATH32(T0b, i4.x) GATH32(T0b, i4.y) GATH32(T0b, i4.z) GATH32(T0b, i4.w)
    }
    if (cv > W_ELL) {
        float4 ov = ((const float4*)(ovfacc1 + (size_t)node * 32))[fl];
        a0 += ov.x; a1 += ov.y; a2 += ov.z; a3 += ov.w;
    }
    float di = dinv[node];
    float d2 = di * di;
    ushort4 o;
    o.x = f2bf(d2 * a0);
    o.y = f2bf(d2 * a1);
    o.z = f2bf(d2 * a2);
    o.w = f2bf(d2 * a3);
    ((ushort4*)(T1b + (size_t)node * 32))[fl] = o;
}

// Overflow pass 2: T1 row atomics into ovfacc2.
__global__ void k_oflow2(const int* __restrict__ ovf, const int* __restrict__ ovf_cnt,
                         const unsigned short* __restrict__ T1b, float* __restrict__ ovfacc2) {
    int n = *ovf_cnt;
    int total = n * 8;
    for (int i = blockIdx.x * blockDim.x + threadIdx.x; i < total;
         i += gridDim.x * blockDim.x) {
        int e = i >> 3, fl = i & 7;
        int src = ovf[2 * e], dst = ovf[2 * e + 1];
        ushort4 u = ((const ushort4*)(T1b + (size_t)src * 32))[fl];
        float* hp = ovfacc2 + (size_t)dst * 32 + fl * 4;
        atomicAdd(hp + 0, bf2f(u.x));
        atomicAdd(hp + 1, bf2f(u.y));
        atomicAdd(hp + 2, bf2f(u.z));
        atomicAdd(hp + 3, bf2f(u.w));
    }
}

// Aggregation 2 + epilogue: out = dinv*(sum T1 + self + ovf + sraw*c1) + b2.
__launch_bounds__(TPB)
__global__ void k_agg2(const int* __restrict__ ell, const unsigned short* __restrict__ T1b,
                       const float* __restrict__ dinv, const int* __restrict__ cnt,
                       const float* __restrict__ ovfacc2, const float* __restrict__ sraw,
                       const float* __restrict__ c1, const float* __restrict__ b2,
                       float* __restrict__ out, int n_nodes) {
    int t = threadIdx.x;
    int lane = t & 63;
    int g = lane >> 3, fl = lane & 7;
    int node = blockIdx.x * 32 + (t >> 6) * 8 + g;
    if (node >= n_nodes) return;
    int cv = cnt[node];
    const int4* ep = (const int4*)(ell + (size_t)node * W_ELL);
    int4 i0 = ep[0], i1 = ep[1], i2 = ep[2], i3 = ep[3];
    ushort4 su = ((const ushort4*)(T1b + (size_t)node * 32))[fl];
    float a0 = bf2f(su.x), a1 = bf2f(su.y), a2 = bf2f(su.z), a3 = bf2f(su.w);
    GATH32(T1b, i0.x) GATH32(T1b, i0.y) GATH32(T1b, i0.z) GATH32(T1b, i0.w)
    GATH32(T1b, i1.x) GATH32(T1b, i1.y) GATH32(T1b, i1.z) GATH32(T1b, i1.w)
    GATH32(T1b, i2.x) GATH32(T1b, i2.y) GATH32(T1b, i2.z) GATH32(T1b, i2.w)
    GATH32(T1b, i3.x) GATH32(T1b, i3.y) GATH32(T1b, i3.z) GATH32(T1b, i3.w)
    if (__any(cv > 16)) {
        int4 i4 = ep[4];
        GATH32(T1b, i4.x) GATH32(T1b, i4.y) GATH32(T1b, i4.z) GATH32(T1b, i4.w)
    }
    if (cv > W_ELL) {
        float4 ov = ((const float4*)(ovfacc2 + (size_t)node * 32))[fl];
        a0 += ov.x; a1 += ov.y; a2 += ov.z; a3 += ov.w;
    }
    float di = dinv[node];
    float sv = sraw[node];
    float4 cc = ((const float4*)c1)[fl];
    float4 bb = ((const float4*)b2)[fl];
    float4 o;
    o.x = di * (a0 + sv * cc.x) + bb.x;
    o.y = di * (a1 + sv * cc.y) + bb.y;
    o.z = di * (a2 + sv * cc.z) + bb.z;
    o.w = di * (a3 + sv * cc.w) + bb.w;
    ((float4*)(out + (size_t)node * 32))[fl] = o;
}

extern "C" void kernel_launch(void* const* d_in, const int* in_sizes, int n_in,
                              void* d_out, int out_size, void* d_ws, size_t ws_size,
                              hipStream_t stream) {
    const float* x  = (const float*)d_in[0];
    const void*  ei = d_in[1];
    const float* W1 = (const float*)d_in[2];
    const float* b1 = (const float*)d_in[3];
    const float* W2 = (const float*)d_in[4];
    const float* b2 = (const float*)d_in[5];
    float* out = (float*)d_out;

    const int n_nodes = in_sizes[0] / 64;
    const int E = in_sizes[1] / 2;
    const int nb = (n_nodes + NPB - 1) / NPB;  // 196 (<= 256)

    char* p = (char*)d_ws;
    auto carve = [&](size_t bytes) {
        char* r = p;
        p += (bytes + 255) / 256 * 256;
        return r;
    };
    int* flag      = (int*)carve(sizeof(int));
    int* bucket_wp = (int*)carve(256 * sizeof(int));
    int* ovf_cnt   = (int*)carve(sizeof(int));
    int* cnt       = (int*)carve((size_t)n_nodes * sizeof(int));
    float* dinv    = (float*)carve(((size_t)n_nodes + 1) * sizeof(float));
    float* sraw    = (float*)carve((size_t)n_nodes * sizeof(float));
    unsigned int* gstage = (unsigned int*)carve((size_t)nb * BCAP * sizeof(unsigned int));
    int* ell       = (int*)carve((size_t)nb * NPB * W_ELL * sizeof(int));
    int* ovf       = (int*)carve((size_t)E * 2 * sizeof(int));
    unsigned short* T0b = (unsigned short*)carve(((size_t)n_nodes + 1) * 32 * sizeof(unsigned short));
    unsigned short* T1b = (unsigned short*)carve(((size_t)n_nodes + 1) * 32 * sizeof(unsigned short));
    float* ovfacc1 = (float*)carve((size_t)n_nodes * 32 * sizeof(float));
    float* ovfacc2 = (float*)carve((size_t)n_nodes * 32 * sizeof(float));
    unsigned short* W12Tb = (unsigned short*)carve(32 * 64 * sizeof(unsigned short));
    float* c1      = (float*)carve(32 * sizeof(float));

    k_detect<<<2, TPB, 0, stream>>>((const unsigned int*)ei, in_sizes[1], flag, bucket_wp,
                                    ovf_cnt, T0b, T1b, dinv, n_nodes, W1, W2, b1, W12Tb, c1);
    k_binA<<<(E + TILE_E - 1) / TILE_E, 512, 0, stream>>>(ei, flag, E, nb, gstage, bucket_wp);
    k_ellB<<<nb, 512, 0, stream>>>(gstage, bucket_wp, ell, cnt, ovf, ovf_cnt, ovfacc1,
                                   ovfacc2, n_nodes);
    k_gemm0<<<(n_nodes + 63) / 64, TPB, 0, stream>>>(x, W12Tb, cnt, dinv, T0b, n_nodes);
    k_s<<<(n_nodes + 63) / 64, TPB, 0, stream>>>(ell, dinv, sraw, n_nodes);
    k_oflow1<<<64, TPB, 0, stream>>>(ovf, ovf_cnt, T0b, dinv, ovfacc1, sraw);
    k_agg1<<<(n_nodes + 31) / 32, TPB, 0, stream>>>(ell, T0b, dinv, cnt, ovfacc1, T1b, n_nodes);
    k_oflow2<<<64, TPB, 0, stream>>>(ovf, ovf_cnt, T1b, ovfacc2);
    k_agg2<<<(n_nodes + 31) / 32, TPB, 0, stream>>>(ell, T1b, dinv, cnt, ovfacc2, sraw, c1,
                                                    b2, out, n_nodes);
}